// Round 7
// baseline (2282.537 us; speedup 1.0000x reference)
//
#include <hip/hip_runtime.h>
#include <hip/hip_bf16.h>

#define T_SEQ 2048
#define BATCH 2
#define CDIM 1024
#define VDIM 256
#define NHEAD 16
#define DHEAD 64
#define NLAYER 8
#define MROWS (BATCH * T_SEQ) /* 4096 */

typedef __attribute__((ext_vector_type(8))) short bf16x8;
typedef __attribute__((ext_vector_type(4))) float f32x4;
typedef __attribute__((ext_vector_type(4))) int i32x4;

// v_perm_b32: sel byte 0-3 -> from 2nd arg, 4-7 -> from 1st arg
#define SELHI 0x07060302u  // top16(a)<<16 | top16(b)
#define SELLO 0x05040100u  // low16(a)<<16 | low16(b)

__device__ __forceinline__ uint prm(uint a, uint b, uint s) { return __builtin_amdgcn_perm(a, b, s); }

__device__ __forceinline__ uint bf16rne(float f) {
    uint u = __float_as_uint(f);
    return (u + 0x7fffu + ((u >> 16) & 1u)) & 0xffff0000u;
}
__device__ __forceinline__ uint packsplit(float x) {
    uint hb = bf16rne(x);
    float d = x - __uint_as_float(hb);
    uint lb = bf16rne(d);
    return prm(hb, lb, SELHI);
}
__device__ __forceinline__ float unpack2(uint u) {
    return __uint_as_float(u & 0xffff0000u) + __uint_as_float(u << 16);
}
__device__ __forceinline__ bf16x8 asb(i32x4 v) {
    union { i32x4 i; bf16x8 b; } u; u.i = v; return u.b;
}
// async global->LDS DMA, 16B per lane: lds slot = base + lane*16
__device__ __forceinline__ void gload_lds16(const void* g, void* l) {
    __builtin_amdgcn_global_load_lds(
        (const __attribute__((address_space(1))) void*)g,
        (__attribute__((address_space(3))) void*)l, 16, 0, 0);
}

// ---------------------------------------------------------------------------
// f32 GEMM (embed / final out / fallback). out_mode 0: f32; 1: packed u32.
// ---------------------------------------------------------------------------
__global__ __launch_bounds__(256) void gemm_f32_kernel(
    const float* __restrict__ A, const float* __restrict__ B,
    const float* __restrict__ bias, const float* __restrict__ addrow,
    float* __restrict__ C, int M, int N, int K, int addmod, int out_mode)
{
    __shared__ float As[16][64];
    __shared__ float Bs[16][68];

    const int tid = threadIdx.x;
    const int bn = blockIdx.x * 64;
    const int bm = blockIdx.y * 64;

    const int lrow = tid >> 2;
    const int lkq  = (tid & 3) * 4;
    const int lkr  = tid >> 4;
    const int lnq  = (tid & 15) * 4;
    const int ty   = tid >> 4;
    const int tx   = tid & 15;

    float acc[4][4];
#pragma unroll
    for (int i = 0; i < 4; ++i)
#pragma unroll
        for (int j = 0; j < 4; ++j) acc[i][j] = 0.f;

    for (int k0 = 0; k0 < K; k0 += 16) {
        __syncthreads();
        {
            float4 a4 = *(const float4*)&A[(size_t)(bm + lrow) * K + k0 + lkq];
            As[lkq + 0][lrow] = a4.x;
            As[lkq + 1][lrow] = a4.y;
            As[lkq + 2][lrow] = a4.z;
            As[lkq + 3][lrow] = a4.w;
            *(float4*)&Bs[lkr][lnq] =
                *(const float4*)&B[(size_t)(k0 + lkr) * N + bn + lnq];
        }
        __syncthreads();
#pragma unroll
        for (int kk = 0; kk < 16; ++kk) {
            const float4 a = *(const float4*)&As[kk][ty * 4];
            const float4 b = *(const float4*)&Bs[kk][tx * 4];
            acc[0][0] += a.x * b.x; acc[0][1] += a.x * b.y; acc[0][2] += a.x * b.z; acc[0][3] += a.x * b.w;
            acc[1][0] += a.y * b.x; acc[1][1] += a.y * b.y; acc[1][2] += a.y * b.z; acc[1][3] += a.y * b.w;
            acc[2][0] += a.z * b.x; acc[2][1] += a.z * b.y; acc[2][2] += a.z * b.z; acc[2][3] += a.z * b.w;
            acc[3][0] += a.w * b.x; acc[3][1] += a.w * b.y; acc[3][2] += a.w * b.z; acc[3][3] += a.w * b.w;
        }
    }

    const int ncol = bn + tx * 4;
    const float4 bv = *(const float4*)&bias[ncol];
#pragma unroll
    for (int i = 0; i < 4; ++i) {
        const int mrow = bm + ty * 4 + i;
        float4 o;
        o.x = acc[i][0] + bv.x;
        o.y = acc[i][1] + bv.y;
        o.z = acc[i][2] + bv.z;
        o.w = acc[i][3] + bv.w;
        if (addrow) {
            const float4 p = *(const float4*)&addrow[(size_t)(mrow % addmod) * N + ncol];
            o.x += p.x; o.y += p.y; o.z += p.z; o.w += p.w;
        }
        if (out_mode == 0) {
            *(float4*)&C[(size_t)mrow * N + ncol] = o;
        } else {
            uint4 pk;
            pk.x = packsplit(o.x); pk.y = packsplit(o.y);
            pk.z = packsplit(o.z); pk.w = packsplit(o.w);
            *(uint4*)&((uint*)C)[(size_t)mrow * N + ncol] = pk;
        }
    }
}

// ---------------------------------------------------------------------------
// Weight pre-split: W[K][N] f32 -> frag-order hi/lo bf16 arrays
// ---------------------------------------------------------------------------
__global__ __launch_bounds__(256) void wsplit_kernel(
    const float* __restrict__ W, short* __restrict__ Fh, short* __restrict__ Fl,
    int N, int K)
{
    const int ln = threadIdx.x & 63, lk = threadIdx.x >> 6;
    const int n  = blockIdx.x * 64 + ln;
    const int kq = blockIdx.y * 4 + lk;
    const int k0 = kq * 4;

    float f0 = W[(size_t)(k0 + 0) * N + n];
    float f1 = W[(size_t)(k0 + 1) * N + n];
    float f2 = W[(size_t)(k0 + 2) * N + n];
    float f3 = W[(size_t)(k0 + 3) * N + n];
    uint h0 = bf16rne(f0), h1 = bf16rne(f1), h2 = bf16rne(f2), h3 = bf16rne(f3);
    uint l0 = bf16rne(f0 - __uint_as_float(h0));
    uint l1 = bf16rne(f1 - __uint_as_float(h1));
    uint l2 = bf16rne(f2 - __uint_as_float(h2));
    uint l3 = bf16rne(f3 - __uint_as_float(h3));

    const int gl = kq & 3, j0 = ((kq >> 2) & 1) * 4;
    const size_t base = (((size_t)(n >> 4) * (K >> 5) + (kq >> 3)) * 64 + gl * 16 + (n & 15)) * 8 + j0;
    *(int2*)&Fh[base] = make_int2((int)prm(h1, h0, SELHI), (int)prm(h3, h2, SELHI));
    *(int2*)&Fl[base] = make_int2((int)prm(l1, l0, SELHI), (int)prm(l3, l2, SELHI));
}

// ---------------------------------------------------------------------------
// MFMA bf16x2 GEMM: 128x128 tile, BK=32, 4 waves. B-tiles staged via
// global_load_lds DMA (frag-linear, no VGPR round-trip); A split via v_perm.
// No registers live across barriers (round-5 spill post-mortem).
// ---------------------------------------------------------------------------
__global__ __launch_bounds__(256) void gemm_mfma_kernel(
    const uint* __restrict__ Ap, const short* __restrict__ Bhf,
    const short* __restrict__ Blf, const float* __restrict__ bias,
    void* __restrict__ Cv, int M, int N, int K, int out_mode)
{
    __shared__ __align__(16) short Ah[8][64][8], Al[8][64][8];
    __shared__ __align__(16) short Bh[8][64][8], Bl[8][64][8];

    const int tid = threadIdx.x, lane = tid & 63, w = tid >> 6;
    const int wr = w >> 1, wc = w & 1, x = lane & 15, gl = lane >> 4;
    const int bm = blockIdx.y * 128, bn = blockIdx.x * 128;
    const int nkc = K >> 5;

    f32x4 acc[4][4];
#pragma unroll
    for (int mi = 0; mi < 4; ++mi)
#pragma unroll
        for (int ni = 0; ni < 4; ++ni) acc[mi][ni] = (f32x4){0.f, 0.f, 0.f, 0.f};

    for (int kc = 0; kc < nkc; ++kc) {
        __syncthreads();
        // ---- stage B via async DMA: wave w handles chunks {w, w+4, w+8, w+12} ----
#pragma unroll
        for (int i = 0; i < 4; ++i) {
            const int c = i * 4 + w;             // wave-uniform
            const int hl = c >> 3, ni = c & 7;
            const short* src = (hl ? Blf : Bhf) +
                (((size_t)((bn >> 4) + ni) * nkc + kc) * 64 + lane) * 8;
            short* dst = (hl ? &Bl[0][0][0] : &Bh[0][0][0]) + (size_t)ni * 512;
            gload_lds16(src, dst);
        }
        // ---- stage A: load packed u32, perm-split to hi/lo frag-linear ----
#pragma unroll
        for (int i = 0; i < 4; ++i) {
            const int f = i * 256 + tid;
            const int r = f >> 3, kq = f & 7;
            const uint4 a = *(const uint4*)&Ap[(size_t)(bm + r) * K + kc * 32 + kq * 4];
            const int mi = r >> 4, dl = (kq & 3) * 16 + (r & 15), j0 = (kq >> 2) * 4;
            *(int2*)&Ah[mi][dl][j0] = make_int2((int)prm(a.y, a.x, SELHI), (int)prm(a.w, a.z, SELHI));
            *(int2*)&Al[mi][dl][j0] = make_int2((int)prm(a.y, a.x, SELLO), (int)prm(a.w, a.z, SELLO));
        }
        __syncthreads();   // drains vmcnt (DMA) + lgkmcnt (ds_write)
        // ---- compute ----
        bf16x8 ah[4], al[4], bh[4], bl[4];
#pragma unroll
        for (int t = 0; t < 4; ++t) {
            ah[t] = *(const bf16x8*)&Ah[wr * 4 + t][lane][0];
            al[t] = *(const bf16x8*)&Al[wr * 4 + t][lane][0];
            bh[t] = *(const bf16x8*)&Bh[wc * 4 + t][lane][0];
            bl[t] = *(const bf16x8*)&Bl[wc * 4 + t][lane][0];
        }
#pragma unroll
        for (int mi = 0; mi < 4; ++mi)
#pragma unroll
            for (int ni = 0; ni < 4; ++ni) {
                acc[mi][ni] = __builtin_amdgcn_mfma_f32_16x16x32_bf16(ah[mi], bh[ni], acc[mi][ni], 0, 0, 0);
                acc[mi][ni] = __builtin_amdgcn_mfma_f32_16x16x32_bf16(ah[mi], bl[ni], acc[mi][ni], 0, 0, 0);
                acc[mi][ni] = __builtin_amdgcn_mfma_f32_16x16x32_bf16(al[mi], bh[ni], acc[mi][ni], 0, 0, 0);
            }
    }

#pragma unroll
    for (int ni = 0; ni < 4; ++ni) {
        const int n = bn + wc * 64 + ni * 16 + x;
        const float bv = bias[n];
#pragma unroll
        for (int mi = 0; mi < 4; ++mi) {
            const int m0 = bm + wr * 64 + mi * 16 + gl * 4;
            const f32x4 o = acc[mi][ni];
            if (out_mode == 0) {
                float* C = (float*)Cv;
                C[(size_t)(m0 + 0) * N + n] = o[0] + bv;
                C[(size_t)(m0 + 1) * N + n] = o[1] + bv;
                C[(size_t)(m0 + 2) * N + n] = o[2] + bv;
                C[(size_t)(m0 + 3) * N + n] = o[3] + bv;
            } else {
                uint* C = (uint*)Cv;
                C[(size_t)(m0 + 0) * N + n] = packsplit(o[0] + bv);
                C[(size_t)(m0 + 1) * N + n] = packsplit(o[1] + bv);
                C[(size_t)(m0 + 2) * N + n] = packsplit(o[2] + bv);
                C[(size_t)(m0 + 3) * N + n] = packsplit(o[3] + bv);
            }
        }
    }
}

// ---------------------------------------------------------------------------
// Flash attention MFMA. QBLK=128, QK^T single-bf16 (hi·hi), PV 3-term bf16x2.
// Register-prefetched K/V staging, 2 barriers/tile. (validated round 5)
// ---------------------------------------------------------------------------
__global__ __launch_bounds__(256) void attn_mfma_kernel(
    const uint* __restrict__ qkv, void* __restrict__ y, int opack)
{
    __shared__ __align__(16) short khi[4][2][64][8];
    __shared__ __align__(16) short vhi[4][2][64][8];
    __shared__ __align__(16) short vlo[4][2][64][8];
    __shared__ uint vpl[64][68];

    const int tid  = threadIdx.x;
    const int w    = tid >> 6;
    const int lane = tid & 63;
    const int x    = lane & 15;
    const int gl   = lane >> 4;
    const int bh = blockIdx.y, b = bh >> 4, hh = bh & 15;
    const int t0 = blockIdx.x * 128;

    i32x4 qhi[2][2];
#pragma unroll
    for (int qf = 0; qf < 2; ++qf) {
        const uint* qp = qkv + (size_t)(b * T_SEQ + t0 + 64 * qf + 16 * w + x) * 3072 + hh * 64;
#pragma unroll
        for (int ch = 0; ch < 2; ++ch) {
            uint4 a0 = *(const uint4*)(qp + 32 * ch + 4 * gl);
            uint4 a1 = *(const uint4*)(qp + 32 * ch + 16 + 4 * gl);
            qhi[qf][ch][0] = (int)prm(a0.y, a0.x, SELHI); qhi[qf][ch][1] = (int)prm(a0.w, a0.z, SELHI);
            qhi[qf][ch][2] = (int)prm(a1.y, a1.x, SELHI); qhi[qf][ch][3] = (int)prm(a1.w, a1.z, SELHI);
        }
    }

    const int rK = tid >> 2, q4 = tid & 3;
    const int sc_s = rK >> 4, xk = rK & 15, chS = q4 >> 1, h2 = q4 & 1;

    const uint* kbase = qkv + (size_t)b * T_SEQ * 3072 + (size_t)rK * 3072 + 1024 + hh * 64 + 16 * q4;
    const uint* vbase = kbase + 1024;

    f32x4 oacc[2][4];
#pragma unroll
    for (int qf = 0; qf < 2; ++qf)
#pragma unroll
        for (int i = 0; i < 4; ++i) oacc[qf][i] = (f32x4){0.f, 0.f, 0.f, 0.f};
    float lsum[2] = {0.f, 0.f};

    uint4 kreg[4], vreg[4];
#pragma unroll
    for (int i = 0; i < 4; ++i) {
        kreg[i] = ((const uint4*)kbase)[i];
        vreg[i] = ((const uint4*)vbase)[i];
    }

    for (int s0 = 0; s0 < T_SEQ; s0 += 64) {
        {
            uint uu[16] = {kreg[0].x, kreg[0].y, kreg[0].z, kreg[0].w,
                           kreg[1].x, kreg[1].y, kreg[1].z, kreg[1].w,
                           kreg[2].x, kreg[2].y, kreg[2].z, kreg[2].w,
                           kreg[3].x, kreg[3].y, kreg[3].z, kreg[3].w};
#pragma unroll
            for (int g = 0; g < 4; ++g) {
                int2 hi2;
                hi2.x = (int)prm(uu[4 * g + 1], uu[4 * g + 0], SELHI);
                hi2.y = (int)prm(uu[4 * g + 3], uu[4 * g + 2], SELHI);
                *(int2*)&khi[sc_s][chS][16 * g + xk][4 * h2] = hi2;
            }
            *(uint4*)&vpl[rK][16 * q4 + 0]  = vreg[0];
            *(uint4*)&vpl[rK][16 * q4 + 4]  = vreg[1];
            *(uint4*)&vpl[rK][16 * q4 + 8]  = vreg[2];
            *(uint4*)&vpl[rK][16 * q4 + 12] = vreg[3];
        }
        __syncthreads();

        if (s0 + 64 < T_SEQ) {
            const uint* kp = kbase + (size_t)(s0 + 64) * 3072;
            const uint* vp = vbase + (size_t)(s0 + 64) * 3072;
#pragma unroll
            for (int i = 0; i < 4; ++i) {
                kreg[i] = ((const uint4*)kp)[i];
                vreg[i] = ((const uint4*)vp)[i];
            }
        }

        f32x4 s4[2][4];
#pragma unroll
        for (int qf = 0; qf < 2; ++qf)
#pragma unroll
            for (int sc = 0; sc < 4; ++sc) s4[qf][sc] = (f32x4){0.f, 0.f, 0.f, 0.f};
#pragma unroll
        for (int sc = 0; sc < 4; ++sc) {
#pragma unroll
            for (int ch = 0; ch < 2; ++ch) {
                bf16x8 kh = *(const bf16x8*)&khi[sc][ch][lane][0];
                s4[0][sc] = __builtin_amdgcn_mfma_f32_16x16x32_bf16(kh, asb(qhi[0][ch]), s4[0][sc], 0, 0, 0);
                s4[1][sc] = __builtin_amdgcn_mfma_f32_16x16x32_bf16(kh, asb(qhi[1][ch]), s4[1][sc], 0, 0, 0);
            }
        }

#pragma unroll
        for (int t2 = 0; t2 < 2; ++t2) {
            const int G = tid + 256 * t2;
            const int lt = G & 63, chv = (G >> 6) & 1, dm = G >> 7;
            const int glt = lt >> 4, xt = lt & 15, col = 16 * dm + xt;
            uint v0 = vpl[32 * chv + 4 * glt + 0][col];
            uint v1 = vpl[32 * chv + 4 * glt + 1][col];
            uint v2 = vpl[32 * chv + 4 * glt + 2][col];
            uint v3 = vpl[32 * chv + 4 * glt + 3][col];
            uint v4 = vpl[32 * chv + 4 * glt + 16][col];
            uint v5 = vpl[32 * chv + 4 * glt + 17][col];
            uint v6 = vpl[32 * chv + 4 * glt + 18][col];
            uint v7 = vpl[32 * chv + 4 * glt + 19][col];
            i32x4 hi4, lo4;
            hi4[0] = (int)prm(v1, v0, SELHI); hi4[1] = (int)prm(v3, v2, SELHI);
            hi4[2] = (int)prm(v5, v4, SELHI); hi4[3] = (int)prm(v7, v6, SELHI);
            lo4[0] = (int)prm(v1, v0, SELLO); lo4[1] = (int)prm(v3, v2, SELLO);
            lo4[2] = (int)prm(v5, v4, SELLO); lo4[3] = (int)prm(v7, v6, SELLO);
            *(i32x4*)&vhi[dm][chv][lt][0] = hi4;
            *(i32x4*)&vlo[dm][chv][lt][0] = lo4;
        }

        i32x4 pfh[2][2], pfl[2][2];
#pragma unroll
        for (int qf = 0; qf < 2; ++qf) {
            f32x4 pc[4];
#pragma unroll
            for (int sc = 0; sc < 4; ++sc) {
                pc[sc][0] = __expf(s4[qf][sc][0] * 0.125f);
                pc[sc][1] = __expf(s4[qf][sc][1] * 0.125f);
                pc[sc][2] = __expf(s4[qf][sc][2] * 0.125f);
                pc[sc][3] = __expf(s4[qf][sc][3] * 0.125f);
                lsum[qf] += pc[sc][0] + pc[sc][1] + pc[sc][2] + pc[sc][3];
            }
#pragma unroll
            for (int c = 0; c < 2; ++c) {
                f32x4 pa = pc[2 * c], pb = pc[2 * c + 1];
                uint a0 = __float_as_uint(pa[0]), a1 = __float_as_uint(pa[1]);
                uint a2 = __float_as_uint(pa[2]), a3 = __float_as_uint(pa[3]);
                uint b0 = __float_as_uint(pb[0]), b1 = __float_as_uint(pb[1]);
                uint b2 = __float_as_uint(pb[2]), b3 = __float_as_uint(pb[3]);
                pfh[qf][c][0] = (int)prm(a1, a0, SELHI); pfh[qf][c][1] = (int)prm(a3, a2, SELHI);
                pfh[qf][c][2] = (int)prm(b1, b0, SELHI); pfh[qf][c][3] = (int)prm(b3, b2, SELHI);
                float d0 = pa[0] - __uint_as_float(a0 & 0xffff0000u);
                float d1 = pa[1] - __uint_as_float(a1 & 0xffff0000u);
                float d2 = pa[2] - __uint_as_float(a2 & 0xffff0000u);
                float d3 = pa[3] - __uint_as_float(a3 & 0xffff0000u);
                float e0 = pb[0] - __uint_as_float(b0 & 0xffff0000u);
                float e1 = pb[1] - __uint_as_float(b1 & 0xffff0000u);
                float e2 = pb[2] - __uint_as_float(b2 & 0xffff0000u);
                float e3 = pb[3] - __uint_as_float(b3 & 0xffff0000u);
                pfl[qf][c][0] = (int)prm(__float_as_uint(d1), __float_as_uint(d0), SELHI);
                pfl[qf][c][1] = (int)prm(__float_as_uint(d3), __float_as_uint(d2), SELHI);
                pfl[qf][c][2] = (int)prm(__float_as_uint(e1), __float_as_uint(e0), SELHI);
                pfl[qf][c][3] = (int)prm(__float_as_uint(e3), __float_as_uint(e2), SELHI);
            }
        }
        __syncthreads();

#pragma unroll
        for (int dm = 0; dm < 4; ++dm) {
#pragma unroll
            for (int ch = 0; ch < 2; ++ch) {
                bf16x8 vh = *(const bf16x8*)&vhi[dm][ch][lane][0];
                bf16x8 vl = *(const bf16x8*)&vlo[dm][ch][lane][0];
#pragma unroll
                for (int qf = 0; qf < 2; ++qf) {
                    oacc[qf][dm] = __builtin_amdgcn_mfma_f32_16x16x32_bf16(vh, asb(pfh[qf][ch]), oacc[qf][dm], 0, 0, 0);
                    oacc[qf][dm] = __builtin_amdgcn_mfma_f32_16x16x32_bf16(vh, asb(pfl[qf][ch]), oacc[qf][dm], 0, 0, 0);
                    oacc[qf][dm] = __builtin_amdgcn_mfma_f32_16x16x32_bf16(vl, asb(pfh[qf][ch]), oacc[qf][dm], 0, 0, 0);
                }
            }
        }
    }

#pragma unroll
    for (int qf = 0; qf < 2; ++qf) {
        float ls = lsum[qf];
        ls += __shfl_xor(ls, 16);
        ls += __shfl_xor(ls, 32);
        const float invl = 1.f / ls;
        const size_t orow = (size_t)(b * T_SEQ + t0 + 64 * qf + 16 * w + x) * CDIM + hh * 64;
        if (opack) {
            uint* yp = (uint*)y + orow;
#pragma unroll
            for (int dm = 0; dm < 4; ++dm) {
                f32x4 o = oacc[qf][dm];
                uint4 pk;
                pk.x = packsplit(o[0] * invl); pk.y = packsplit(o[1] * invl);
                pk.z = packsplit(o[2] * invl); pk.w = packsplit(o[3] * invl);
                *(uint4*)(yp + 16 * dm + 4 * gl) = pk;
            }
        } else {
            float* yp = (float*)y + orow;
#pragma unroll
            for (int dm = 0; dm < 4; ++dm) {
                f32x4 o = oacc[qf][dm];
                o[0] *= invl; o[1] *= invl; o[2] *= invl; o[3] *= invl;
                *(f32x4*)(yp + 16 * dm + 4 * gl) = o;
            }
        }
    }
}

// ---------------------------------------------------------------------------
// LayerNorm; input f32 or packed u32 per flag.
// ---------------------------------------------------------------------------
__global__ __launch_bounds__(256) void ln_kernel(
    const void* __restrict__ h, const float* __restrict__ gamma,
    const float* __restrict__ beta, float* __restrict__ out, int packed)
{
    const int row = blockIdx.x;
    const int tid = threadIdx.x;

    float4 v;
    if (packed) {
        uint4 u = *(const uint4*)&((const uint*)h)[(size_t)row * CDIM + tid * 4];
        v.x = unpack2(u.x); v.y = unpack2(u.y); v.z = unpack2(u.z); v.w = unpack2(u.w);
    } else {
        v = *(const float4*)&((const float*)h)[(size_t)row * CDIM + tid * 4];
    }
    float s  = v.x + v.y + v.z + v.w;
    float ss = v.x * v.x + v.y * v.y + v.z * v.z + v.w * v.w;
#pragma unroll
    for (int off = 1; off < 64; off <<= 1) {
        s  += __shfl_xor(s, off);
        ss += __shfl_xor(ss, off);
    }
    __shared__ float rs[4], rss[4];
    const int wid = tid >> 6;
    if ((tid & 63) == 0) { rs[wid] = s; rss[wid] = ss; }
    __syncthreads();
    s  = rs[0] + rs[1] + rs[2] + rs[3];
    ss = rss[0] + rss[1] + rss[2] + rss[3];

    const float mu   = s * (1.f / (float)CDIM);
    const float var  = ss * (1.f / (float)CDIM) - mu * mu;
    const float rstd = rsqrtf(var + 1e-5f);

    const float4 g  = *(const float4*)&gamma[tid * 4];
    const float4 be = *(const float4*)&beta[tid * 4];
    float4 o;
    o.x = (v.x - mu) * rstd * g.x + be.x;
    o.y = (v.y - mu) * rstd * g.y + be.y;
    o.z = (v.z - mu) * rstd * g.z + be.z;
    o.w = (v.w - mu) * rstd * g.w + be.w;
    *(float4*)&out[(size_t)row * CDIM + tid * 4] = o;
}

// ---------------------------------------------------------------------------
extern "C" void kernel_launch(void* const* d_in, const int* in_sizes, int n_in,
                              void* d_out, int out_size, void* d_ws, size_t ws_size,
                              hipStream_t stream)
{
    const float* x      = (const float*)d_in[0];
    const float* W_emb  = (const float*)d_in[1];
    const float* b_emb  = (const float*)d_in[2];
    const float* pos    = (const float*)d_in[3];
    const float* Wqkv   = (const float*)d_in[4];
    const float* bqkv   = (const float*)d_in[5];
    const float* Wproj  = (const float*)d_in[6];
    const float* bproj  = (const float*)d_in[7];
    const float* gamma  = (const float*)d_in[8];
    const float* beta   = (const float*)d_in[9];
    const float* W_out  = (const float*)d_in[10];
    const float* b_out  = (const float*)d_in[11];
    float* out = (float*)d_out;

    uint* h    = (uint*)d_ws;
    uint* qkvp = h + (size_t)MROWS * CDIM;
    uint* y    = qkvp + (size_t)MROWS * 3 * CDIM;
    short* Bqh = (short*)(y + (size_t)MROWS * CDIM);
    short* Bql = Bqh + (size_t)3 * CDIM * CDIM;
    short* Bph = Bql + (size_t)3 * CDIM * CDIM;
    short* Bpl = Bph + (size_t)CDIM * CDIM;

    const size_t need = ((size_t)MROWS * CDIM * 5) * 4 +
                        ((size_t)3 * CDIM * CDIM * 2 + (size_t)CDIM * CDIM * 2) * 2;
    const bool use_mfma = ws_size >= need;

    const dim3 blk(256);

    if (use_mfma) {
        gemm_f32_kernel<<<dim3(CDIM / 64, MROWS / 64), blk, 0, stream>>>(
            x, W_emb, b_emb, pos, (float*)h, MROWS, CDIM, VDIM, T_SEQ, 1);
        for (int l = 0; l < NLAYER; ++l) {
            wsplit_kernel<<<dim3(3 * CDIM / 64, CDIM / 16), blk, 0, stream>>>(
                Wqkv + (size_t)l * CDIM * 3 * CDIM, Bqh, Bql, 3 * CDIM, CDIM);
            gemm_mfma_kernel<<<dim3(3 * CDIM / 128, MROWS / 128), blk, 0, stream>>>(
                h, Bqh, Bql, bqkv + (size_t)l * 3 * CDIM, qkvp, MROWS, 3 * CDIM, CDIM, 1);
            attn_mfma_kernel<<<dim3(T_SEQ / 128, BATCH * NHEAD), blk, 0, stream>>>(
                qkvp, y, 1);
            wsplit_kernel<<<dim3(CDIM / 64, CDIM / 16), blk, 0, stream>>>(
                Wproj + (size_t)l * CDIM * CDIM, Bph, Bpl, CDIM, CDIM);
            gemm_mfma_kernel<<<dim3(CDIM / 128, MROWS / 128), blk, 0, stream>>>(
                y, Bph, Bpl, bproj + (size_t)l * CDIM, h, MROWS, CDIM, CDIM, 1);
        }
        ln_kernel<<<dim3(MROWS), blk, 0, stream>>>(h, gamma, beta, (float*)y, 1);
    } else {
        gemm_f32_kernel<<<dim3(CDIM / 64, MROWS / 64), blk, 0, stream>>>(
            x, W_emb, b_emb, pos, (float*)h, MROWS, CDIM, VDIM, T_SEQ, 0);
        for (int l = 0; l < NLAYER; ++l) {
            gemm_f32_kernel<<<dim3(3 * CDIM / 64, MROWS / 64), blk, 0, stream>>>(
                (float*)h, Wqkv + (size_t)l * CDIM * 3 * CDIM, bqkv + (size_t)l * 3 * CDIM,
                nullptr, (float*)qkvp, MROWS, 3 * CDIM, CDIM, 1, 1);
            attn_mfma_kernel<<<dim3(T_SEQ / 128, BATCH * NHEAD), blk, 0, stream>>>(
                qkvp, y, 0);
            gemm_f32_kernel<<<dim3(CDIM / 64, MROWS / 64), blk, 0, stream>>>(
                (float*)y, Wproj + (size_t)l * CDIM * CDIM, bproj + (size_t)l * CDIM,
                nullptr, (float*)h, MROWS, CDIM, CDIM, 1, 0);
        }
        ln_kernel<<<dim3(MROWS), blk, 0, stream>>>(h, gamma, beta, (float*)y, 0);
    }

    gemm_f32_kernel<<<dim3(VDIM / 64, MROWS / 64), blk, 0, stream>>>(
        (float*)y, W_out, b_out, nullptr, out, MROWS, VDIM, CDIM, 1, 0);
}

// Round 8
// 2220.974 us; speedup vs baseline: 1.0277x; 1.0277x over previous
//
#include <hip/hip_runtime.h>
#include <hip/hip_bf16.h>

#define T_SEQ 2048
#define BATCH 2
#define CDIM 1024
#define VDIM 256
#define NHEAD 16
#define DHEAD 64
#define NLAYER 8
#define MROWS (BATCH * T_SEQ) /* 4096 */

typedef __attribute__((ext_vector_type(8))) short bf16x8;
typedef __attribute__((ext_vector_type(4))) float f32x4;
typedef __attribute__((ext_vector_type(4))) int i32x4;

// v_perm_b32: sel byte 0-3 -> from 2nd arg, 4-7 -> from 1st arg
#define SELHI 0x07060302u  // top16(a)<<16 | top16(b)
#define SELLO 0x05040100u  // low16(a)<<16 | low16(b)

__device__ __forceinline__ uint prm(uint a, uint b, uint s) { return __builtin_amdgcn_perm(a, b, s); }

__device__ __forceinline__ uint bf16rne(float f) {
    uint u = __float_as_uint(f);
    return (u + 0x7fffu + ((u >> 16) & 1u)) & 0xffff0000u;
}
__device__ __forceinline__ uint packsplit(float x) {
    uint hb = bf16rne(x);
    float d = x - __uint_as_float(hb);
    uint lb = bf16rne(d);
    return prm(hb, lb, SELHI);
}
__device__ __forceinline__ float unpack2(uint u) {
    return __uint_as_float(u & 0xffff0000u) + __uint_as_float(u << 16);
}
__device__ __forceinline__ bf16x8 asb(i32x4 v) {
    union { i32x4 i; bf16x8 b; } u; u.i = v; return u.b;
}
// async global->LDS DMA, 16B per lane: lds slot = base + lane*16
__device__ __forceinline__ void gload_lds16(const void* g, void* l) {
    __builtin_amdgcn_global_load_lds(
        (const __attribute__((address_space(1))) void*)g,
        (__attribute__((address_space(3))) void*)l, 16, 0, 0);
}

// ---------------------------------------------------------------------------
// f32 GEMM (embed / final out / fallback). out_mode 0: f32; 1: packed u32.
// ---------------------------------------------------------------------------
__global__ __launch_bounds__(256) void gemm_f32_kernel(
    const float* __restrict__ A, const float* __restrict__ B,
    const float* __restrict__ bias, const float* __restrict__ addrow,
    float* __restrict__ C, int M, int N, int K, int addmod, int out_mode)
{
    __shared__ float As[16][64];
    __shared__ float Bs[16][68];

    const int tid = threadIdx.x;
    const int bn = blockIdx.x * 64;
    const int bm = blockIdx.y * 64;

    const int lrow = tid >> 2;
    const int lkq  = (tid & 3) * 4;
    const int lkr  = tid >> 4;
    const int lnq  = (tid & 15) * 4;
    const int ty   = tid >> 4;
    const int tx   = tid & 15;

    float acc[4][4];
#pragma unroll
    for (int i = 0; i < 4; ++i)
#pragma unroll
        for (int j = 0; j < 4; ++j) acc[i][j] = 0.f;

    for (int k0 = 0; k0 < K; k0 += 16) {
        __syncthreads();
        {
            float4 a4 = *(const float4*)&A[(size_t)(bm + lrow) * K + k0 + lkq];
            As[lkq + 0][lrow] = a4.x;
            As[lkq + 1][lrow] = a4.y;
            As[lkq + 2][lrow] = a4.z;
            As[lkq + 3][lrow] = a4.w;
            *(float4*)&Bs[lkr][lnq] =
                *(const float4*)&B[(size_t)(k0 + lkr) * N + bn + lnq];
        }
        __syncthreads();
#pragma unroll
        for (int kk = 0; kk < 16; ++kk) {
            const float4 a = *(const float4*)&As[kk][ty * 4];
            const float4 b = *(const float4*)&Bs[kk][tx * 4];
            acc[0][0] += a.x * b.x; acc[0][1] += a.x * b.y; acc[0][2] += a.x * b.z; acc[0][3] += a.x * b.w;
            acc[1][0] += a.y * b.x; acc[1][1] += a.y * b.y; acc[1][2] += a.y * b.z; acc[1][3] += a.y * b.w;
            acc[2][0] += a.z * b.x; acc[2][1] += a.z * b.y; acc[2][2] += a.z * b.z; acc[2][3] += a.z * b.w;
            acc[3][0] += a.w * b.x; acc[3][1] += a.w * b.y; acc[3][2] += a.w * b.z; acc[3][3] += a.w * b.w;
        }
    }

    const int ncol = bn + tx * 4;
    const float4 bv = *(const float4*)&bias[ncol];
#pragma unroll
    for (int i = 0; i < 4; ++i) {
        const int mrow = bm + ty * 4 + i;
        float4 o;
        o.x = acc[i][0] + bv.x;
        o.y = acc[i][1] + bv.y;
        o.z = acc[i][2] + bv.z;
        o.w = acc[i][3] + bv.w;
        if (addrow) {
            const float4 p = *(const float4*)&addrow[(size_t)(mrow % addmod) * N + ncol];
            o.x += p.x; o.y += p.y; o.z += p.z; o.w += p.w;
        }
        if (out_mode == 0) {
            *(float4*)&C[(size_t)mrow * N + ncol] = o;
        } else {
            uint4 pk;
            pk.x = packsplit(o.x); pk.y = packsplit(o.y);
            pk.z = packsplit(o.z); pk.w = packsplit(o.w);
            *(uint4*)&((uint*)C)[(size_t)mrow * N + ncol] = pk;
        }
    }
}

// ---------------------------------------------------------------------------
// Weight pre-split: W[K][N] f32 -> frag-order hi/lo bf16 arrays
// ---------------------------------------------------------------------------
__global__ __launch_bounds__(256) void wsplit_kernel(
    const float* __restrict__ W, short* __restrict__ Fh, short* __restrict__ Fl,
    int N, int K)
{
    const int ln = threadIdx.x & 63, lk = threadIdx.x >> 6;
    const int n  = blockIdx.x * 64 + ln;
    const int kq = blockIdx.y * 4 + lk;
    const int k0 = kq * 4;

    float f0 = W[(size_t)(k0 + 0) * N + n];
    float f1 = W[(size_t)(k0 + 1) * N + n];
    float f2 = W[(size_t)(k0 + 2) * N + n];
    float f3 = W[(size_t)(k0 + 3) * N + n];
    uint h0 = bf16rne(f0), h1 = bf16rne(f1), h2 = bf16rne(f2), h3 = bf16rne(f3);
    uint l0 = bf16rne(f0 - __uint_as_float(h0));
    uint l1 = bf16rne(f1 - __uint_as_float(h1));
    uint l2 = bf16rne(f2 - __uint_as_float(h2));
    uint l3 = bf16rne(f3 - __uint_as_float(h3));

    const int gl = kq & 3, j0 = ((kq >> 2) & 1) * 4;
    const size_t base = (((size_t)(n >> 4) * (K >> 5) + (kq >> 3)) * 64 + gl * 16 + (n & 15)) * 8 + j0;
    *(int2*)&Fh[base] = make_int2((int)prm(h1, h0, SELHI), (int)prm(h3, h2, SELHI));
    *(int2*)&Fl[base] = make_int2((int)prm(l1, l0, SELHI), (int)prm(l3, l2, SELHI));
}

// ---------------------------------------------------------------------------
// MFMA bf16x2 GEMM: 128x128 tile, BK=32, 4 waves. B-tiles staged via
// global_load_lds DMA; A split via v_perm. (validated round 7)
// ---------------------------------------------------------------------------
__global__ __launch_bounds__(256) void gemm_mfma_kernel(
    const uint* __restrict__ Ap, const short* __restrict__ Bhf,
    const short* __restrict__ Blf, const float* __restrict__ bias,
    void* __restrict__ Cv, int M, int N, int K, int out_mode)
{
    __shared__ __align__(16) short Ah[8][64][8], Al[8][64][8];
    __shared__ __align__(16) short Bh[8][64][8], Bl[8][64][8];

    const int tid = threadIdx.x, lane = tid & 63, w = tid >> 6;
    const int wr = w >> 1, wc = w & 1, x = lane & 15, gl = lane >> 4;
    const int bm = blockIdx.y * 128, bn = blockIdx.x * 128;
    const int nkc = K >> 5;

    f32x4 acc[4][4];
#pragma unroll
    for (int mi = 0; mi < 4; ++mi)
#pragma unroll
        for (int ni = 0; ni < 4; ++ni) acc[mi][ni] = (f32x4){0.f, 0.f, 0.f, 0.f};

    for (int kc = 0; kc < nkc; ++kc) {
        __syncthreads();
#pragma unroll
        for (int i = 0; i < 4; ++i) {
            const int c = i * 4 + w;             // wave-uniform
            const int hl = c >> 3, ni = c & 7;
            const short* src = (hl ? Blf : Bhf) +
                (((size_t)((bn >> 4) + ni) * nkc + kc) * 64 + lane) * 8;
            short* dst = (hl ? &Bl[0][0][0] : &Bh[0][0][0]) + (size_t)ni * 512;
            gload_lds16(src, dst);
        }
#pragma unroll
        for (int i = 0; i < 4; ++i) {
            const int f = i * 256 + tid;
            const int r = f >> 3, kq = f & 7;
            const uint4 a = *(const uint4*)&Ap[(size_t)(bm + r) * K + kc * 32 + kq * 4];
            const int mi = r >> 4, dl = (kq & 3) * 16 + (r & 15), j0 = (kq >> 2) * 4;
            *(int2*)&Ah[mi][dl][j0] = make_int2((int)prm(a.y, a.x, SELHI), (int)prm(a.w, a.z, SELHI));
            *(int2*)&Al[mi][dl][j0] = make_int2((int)prm(a.y, a.x, SELLO), (int)prm(a.w, a.z, SELLO));
        }
        __syncthreads();   // drains vmcnt (DMA) + lgkmcnt (ds_write)
        bf16x8 ah[4], al[4], bh[4], bl[4];
#pragma unroll
        for (int t = 0; t < 4; ++t) {
            ah[t] = *(const bf16x8*)&Ah[wr * 4 + t][lane][0];
            al[t] = *(const bf16x8*)&Al[wr * 4 + t][lane][0];
            bh[t] = *(const bf16x8*)&Bh[wc * 4 + t][lane][0];
            bl[t] = *(const bf16x8*)&Bl[wc * 4 + t][lane][0];
        }
#pragma unroll
        for (int mi = 0; mi < 4; ++mi)
#pragma unroll
            for (int ni = 0; ni < 4; ++ni) {
                acc[mi][ni] = __builtin_amdgcn_mfma_f32_16x16x32_bf16(ah[mi], bh[ni], acc[mi][ni], 0, 0, 0);
                acc[mi][ni] = __builtin_amdgcn_mfma_f32_16x16x32_bf16(ah[mi], bl[ni], acc[mi][ni], 0, 0, 0);
                acc[mi][ni] = __builtin_amdgcn_mfma_f32_16x16x32_bf16(al[mi], bh[ni], acc[mi][ni], 0, 0, 0);
            }
    }

#pragma unroll
    for (int ni = 0; ni < 4; ++ni) {
        const int n = bn + wc * 64 + ni * 16 + x;
        const float bv = bias[n];
#pragma unroll
        for (int mi = 0; mi < 4; ++mi) {
            const int m0 = bm + wr * 64 + mi * 16 + gl * 4;
            const f32x4 o = acc[mi][ni];
            if (out_mode == 0) {
                float* C = (float*)Cv;
                C[(size_t)(m0 + 0) * N + n] = o[0] + bv;
                C[(size_t)(m0 + 1) * N + n] = o[1] + bv;
                C[(size_t)(m0 + 2) * N + n] = o[2] + bv;
                C[(size_t)(m0 + 3) * N + n] = o[3] + bv;
            } else {
                uint* C = (uint*)Cv;
                C[(size_t)(m0 + 0) * N + n] = packsplit(o[0] + bv);
                C[(size_t)(m0 + 1) * N + n] = packsplit(o[1] + bv);
                C[(size_t)(m0 + 2) * N + n] = packsplit(o[2] + bv);
                C[(size_t)(m0 + 3) * N + n] = packsplit(o[3] + bv);
            }
        }
    }
}

// ---------------------------------------------------------------------------
// Flash attention MFMA. QBLK=128, QK^T single-bf16 (hi·hi), PV 2-term
// (vh·ph + vh·pl; V RNE-bf16 unbiased). XCD-swizzled 1-D grid (512 blocks):
// each XCD owns 4 heads x all 16 q-tiles -> K/V L2-resident (4 MB/XCD).
// Register-prefetched K/V staging, 2 barriers/tile, setprio on MFMA clusters.
// ---------------------------------------------------------------------------
__global__ __launch_bounds__(256) void attn_mfma_kernel(
    const uint* __restrict__ qkv, void* __restrict__ y, int opack)
{
    __shared__ __align__(16) short khi[4][2][64][8];
    __shared__ __align__(16) short vhi[4][2][64][8];
    __shared__ uint vpl[64][68];

    const int tid  = threadIdx.x;
    const int w    = tid >> 6;
    const int lane = tid & 63;
    const int x    = lane & 15;
    const int gl   = lane >> 4;

    // T1 XCD swizzle: orig%8 = XCD (heuristic); give each XCD a contiguous
    // 64-block chunk = 4 bh x 16 q-tiles.
    const int orig = blockIdx.x;
    const int wgid = (orig & 7) * 64 + (orig >> 3);
    const int bh = wgid >> 4;
    const int b = bh >> 4, hh = bh & 15;
    const int t0 = (wgid & 15) * 128;

    i32x4 qhi[2][2];
#pragma unroll
    for (int qf = 0; qf < 2; ++qf) {
        const uint* qp = qkv + (size_t)(b * T_SEQ + t0 + 64 * qf + 16 * w + x) * 3072 + hh * 64;
#pragma unroll
        for (int ch = 0; ch < 2; ++ch) {
            uint4 a0 = *(const uint4*)(qp + 32 * ch + 4 * gl);
            uint4 a1 = *(const uint4*)(qp + 32 * ch + 16 + 4 * gl);
            qhi[qf][ch][0] = (int)prm(a0.y, a0.x, SELHI); qhi[qf][ch][1] = (int)prm(a0.w, a0.z, SELHI);
            qhi[qf][ch][2] = (int)prm(a1.y, a1.x, SELHI); qhi[qf][ch][3] = (int)prm(a1.w, a1.z, SELHI);
        }
    }

    const int rK = tid >> 2, q4 = tid & 3;
    const int sc_s = rK >> 4, xk = rK & 15, chS = q4 >> 1, h2 = q4 & 1;

    const uint* kbase = qkv + (size_t)b * T_SEQ * 3072 + (size_t)rK * 3072 + 1024 + hh * 64 + 16 * q4;
    const uint* vbase = kbase + 1024;

    f32x4 oacc[2][4];
#pragma unroll
    for (int qf = 0; qf < 2; ++qf)
#pragma unroll
        for (int i = 0; i < 4; ++i) oacc[qf][i] = (f32x4){0.f, 0.f, 0.f, 0.f};
    float lsum[2] = {0.f, 0.f};

    uint4 kreg[4], vreg[4];
#pragma unroll
    for (int i = 0; i < 4; ++i) {
        kreg[i] = ((const uint4*)kbase)[i];
        vreg[i] = ((const uint4*)vbase)[i];
    }

    for (int s0 = 0; s0 < T_SEQ; s0 += 64) {
        // ---- write staged K (hi-split) + V (plain) to LDS ----
        {
            uint uu[16] = {kreg[0].x, kreg[0].y, kreg[0].z, kreg[0].w,
                           kreg[1].x, kreg[1].y, kreg[1].z, kreg[1].w,
                           kreg[2].x, kreg[2].y, kreg[2].z, kreg[2].w,
                           kreg[3].x, kreg[3].y, kreg[3].z, kreg[3].w};
#pragma unroll
            for (int g = 0; g < 4; ++g) {
                int2 hi2;
                hi2.x = (int)prm(uu[4 * g + 1], uu[4 * g + 0], SELHI);
                hi2.y = (int)prm(uu[4 * g + 3], uu[4 * g + 2], SELHI);
                *(int2*)&khi[sc_s][chS][16 * g + xk][4 * h2] = hi2;
            }
            *(uint4*)&vpl[rK][16 * q4 + 0]  = vreg[0];
            *(uint4*)&vpl[rK][16 * q4 + 4]  = vreg[1];
            *(uint4*)&vpl[rK][16 * q4 + 8]  = vreg[2];
            *(uint4*)&vpl[rK][16 * q4 + 12] = vreg[3];
        }
        __syncthreads();

        // ---- issue next-tile global loads (latency hidden under compute) ----
        if (s0 + 64 < T_SEQ) {
            const uint* kp = kbase + (size_t)(s0 + 64) * 3072;
            const uint* vp = vbase + (size_t)(s0 + 64) * 3072;
#pragma unroll
            for (int i = 0; i < 4; ++i) {
                kreg[i] = ((const uint4*)kp)[i];
                vreg[i] = ((const uint4*)vp)[i];
            }
        }

        // ---- S^T = K·Q^T (hi·hi) ----
        f32x4 s4[2][4];
#pragma unroll
        for (int qf = 0; qf < 2; ++qf)
#pragma unroll
            for (int sc = 0; sc < 4; ++sc) s4[qf][sc] = (f32x4){0.f, 0.f, 0.f, 0.f};
        __builtin_amdgcn_s_setprio(1);
#pragma unroll
        for (int sc = 0; sc < 4; ++sc) {
#pragma unroll
            for (int ch = 0; ch < 2; ++ch) {
                bf16x8 kh = *(const bf16x8*)&khi[sc][ch][lane][0];
                s4[0][sc] = __builtin_amdgcn_mfma_f32_16x16x32_bf16(kh, asb(qhi[0][ch]), s4[0][sc], 0, 0, 0);
                s4[1][sc] = __builtin_amdgcn_mfma_f32_16x16x32_bf16(kh, asb(qhi[1][ch]), s4[1][sc], 0, 0, 0);
            }
        }
        __builtin_amdgcn_s_setprio(0);

        // ---- repack V -> frag-linear hi only (2-term PV) ----
#pragma unroll
        for (int t2 = 0; t2 < 2; ++t2) {
            const int G = tid + 256 * t2;
            const int lt = G & 63, chv = (G >> 6) & 1, dm = G >> 7;
            const int glt = lt >> 4, xt = lt & 15, col = 16 * dm + xt;
            uint v0 = vpl[32 * chv + 4 * glt + 0][col];
            uint v1 = vpl[32 * chv + 4 * glt + 1][col];
            uint v2 = vpl[32 * chv + 4 * glt + 2][col];
            uint v3 = vpl[32 * chv + 4 * glt + 3][col];
            uint v4 = vpl[32 * chv + 4 * glt + 16][col];
            uint v5 = vpl[32 * chv + 4 * glt + 17][col];
            uint v6 = vpl[32 * chv + 4 * glt + 18][col];
            uint v7 = vpl[32 * chv + 4 * glt + 19][col];
            i32x4 hi4;
            hi4[0] = (int)prm(v1, v0, SELHI); hi4[1] = (int)prm(v3, v2, SELHI);
            hi4[2] = (int)prm(v5, v4, SELHI); hi4[3] = (int)prm(v7, v6, SELHI);
            *(i32x4*)&vhi[dm][chv][lt][0] = hi4;
        }

        // ---- softmax + P hi/lo pack (per q-frag) ----
        i32x4 pfh[2][2], pfl[2][2];
#pragma unroll
        for (int qf = 0; qf < 2; ++qf) {
            f32x4 pc[4];
#pragma unroll
            for (int sc = 0; sc < 4; ++sc) {
                pc[sc][0] = __expf(s4[qf][sc][0] * 0.125f);
                pc[sc][1] = __expf(s4[qf][sc][1] * 0.125f);
                pc[sc][2] = __expf(s4[qf][sc][2] * 0.125f);
                pc[sc][3] = __expf(s4[qf][sc][3] * 0.125f);
                lsum[qf] += pc[sc][0] + pc[sc][1] + pc[sc][2] + pc[sc][3];
            }
#pragma unroll
            for (int c = 0; c < 2; ++c) {
                f32x4 pa = pc[2 * c], pb = pc[2 * c + 1];
                uint a0 = __float_as_uint(pa[0]), a1 = __float_as_uint(pa[1]);
                uint a2 = __float_as_uint(pa[2]), a3 = __float_as_uint(pa[3]);
                uint b0 = __float_as_uint(pb[0]), b1 = __float_as_uint(pb[1]);
                uint b2 = __float_as_uint(pb[2]), b3 = __float_as_uint(pb[3]);
                pfh[qf][c][0] = (int)prm(a1, a0, SELHI); pfh[qf][c][1] = (int)prm(a3, a2, SELHI);
                pfh[qf][c][2] = (int)prm(b1, b0, SELHI); pfh[qf][c][3] = (int)prm(b3, b2, SELHI);
                float d0 = pa[0] - __uint_as_float(a0 & 0xffff0000u);
                float d1 = pa[1] - __uint_as_float(a1 & 0xffff0000u);
                float d2 = pa[2] - __uint_as_float(a2 & 0xffff0000u);
                float d3 = pa[3] - __uint_as_float(a3 & 0xffff0000u);
                float e0 = pb[0] - __uint_as_float(b0 & 0xffff0000u);
                float e1 = pb[1] - __uint_as_float(b1 & 0xffff0000u);
                float e2 = pb[2] - __uint_as_float(b2 & 0xffff0000u);
                float e3 = pb[3] - __uint_as_float(b3 & 0xffff0000u);
                pfl[qf][c][0] = (int)prm(__float_as_uint(d1), __float_as_uint(d0), SELHI);
                pfl[qf][c][1] = (int)prm(__float_as_uint(d3), __float_as_uint(d2), SELHI);
                pfl[qf][c][2] = (int)prm(__float_as_uint(e1), __float_as_uint(e0), SELHI);
                pfl[qf][c][3] = (int)prm(__float_as_uint(e3), __float_as_uint(e2), SELHI);
            }
        }
        __syncthreads();  // V repack complete; fences next-tile LDS writes

        // ---- O^T += V^T·P^T (2-term: vh·ph + vh·pl) ----
        __builtin_amdgcn_s_setprio(1);
#pragma unroll
        for (int dm = 0; dm < 4; ++dm) {
#pragma unroll
            for (int ch = 0; ch < 2; ++ch) {
                bf16x8 vh = *(const bf16x8*)&vhi[dm][ch][lane][0];
#pragma unroll
                for (int qf = 0; qf < 2; ++qf) {
                    oacc[qf][dm] = __builtin_amdgcn_mfma_f32_16x16x32_bf16(vh, asb(pfh[qf][ch]), oacc[qf][dm], 0, 0, 0);
                    oacc[qf][dm] = __builtin_amdgcn_mfma_f32_16x16x32_bf16(vh, asb(pfl[qf][ch]), oacc[qf][dm], 0, 0, 0);
                }
            }
        }
        __builtin_amdgcn_s_setprio(0);
    }

#pragma unroll
    for (int qf = 0; qf < 2; ++qf) {
        float ls = lsum[qf];
        ls += __shfl_xor(ls, 16);
        ls += __shfl_xor(ls, 32);
        const float invl = 1.f / ls;
        const size_t orow = (size_t)(b * T_SEQ + t0 + 64 * qf + 16 * w + x) * CDIM + hh * 64;
        if (opack) {
            uint* yp = (uint*)y + orow;
#pragma unroll
            for (int dm = 0; dm < 4; ++dm) {
                f32x4 o = oacc[qf][dm];
                uint4 pk;
                pk.x = packsplit(o[0] * invl); pk.y = packsplit(o[1] * invl);
                pk.z = packsplit(o[2] * invl); pk.w = packsplit(o[3] * invl);
                *(uint4*)(yp + 16 * dm + 4 * gl) = pk;
            }
        } else {
            float* yp = (float*)y + orow;
#pragma unroll
            for (int dm = 0; dm < 4; ++dm) {
                f32x4 o = oacc[qf][dm];
                o[0] *= invl; o[1] *= invl; o[2] *= invl; o[3] *= invl;
                *(f32x4*)(yp + 16 * dm + 4 * gl) = o;
            }
        }
    }
}

// ---------------------------------------------------------------------------
// LayerNorm; input f32 or packed u32 per flag.
// ---------------------------------------------------------------------------
__global__ __launch_bounds__(256) void ln_kernel(
    const void* __restrict__ h, const float* __restrict__ gamma,
    const float* __restrict__ beta, float* __restrict__ out, int packed)
{
    const int row = blockIdx.x;
    const int tid = threadIdx.x;

    float4 v;
    if (packed) {
        uint4 u = *(const uint4*)&((const uint*)h)[(size_t)row * CDIM + tid * 4];
        v.x = unpack2(u.x); v.y = unpack2(u.y); v.z = unpack2(u.z); v.w = unpack2(u.w);
    } else {
        v = *(const float4*)&((const float*)h)[(size_t)row * CDIM + tid * 4];
    }
    float s  = v.x + v.y + v.z + v.w;
    float ss = v.x * v.x + v.y * v.y + v.z * v.z + v.w * v.w;
#pragma unroll
    for (int off = 1; off < 64; off <<= 1) {
        s  += __shfl_xor(s, off);
        ss += __shfl_xor(ss, off);
    }
    __shared__ float rs[4], rss[4];
    const int wid = tid >> 6;
    if ((tid & 63) == 0) { rs[wid] = s; rss[wid] = ss; }
    __syncthreads();
    s  = rs[0] + rs[1] + rs[2] + rs[3];
    ss = rss[0] + rss[1] + rss[2] + rss[3];

    const float mu   = s * (1.f / (float)CDIM);
    const float var  = ss * (1.f / (float)CDIM) - mu * mu;
    const float rstd = rsqrtf(var + 1e-5f);

    const float4 g  = *(const float4*)&gamma[tid * 4];
    const float4 be = *(const float4*)&beta[tid * 4];
    float4 o;
    o.x = (v.x - mu) * rstd * g.x + be.x;
    o.y = (v.y - mu) * rstd * g.y + be.y;
    o.z = (v.z - mu) * rstd * g.z + be.z;
    o.w = (v.w - mu) * rstd * g.w + be.w;
    *(float4*)&out[(size_t)row * CDIM + tid * 4] = o;
}

// ---------------------------------------------------------------------------
extern "C" void kernel_launch(void* const* d_in, const int* in_sizes, int n_in,
                              void* d_out, int out_size, void* d_ws, size_t ws_size,
                              hipStream_t stream)
{
    const float* x      = (const float*)d_in[0];
    const float* W_emb  = (const float*)d_in[1];
    const float* b_emb  = (const float*)d_in[2];
    const float* pos    = (const float*)d_in[3];
    const float* Wqkv   = (const float*)d_in[4];
    const float* bqkv   = (const float*)d_in[5];
    const float* Wproj  = (const float*)d_in[6];
    const float* bproj  = (const float*)d_in[7];
    const float* gamma  = (const float*)d_in[8];
    const float* beta   = (const float*)d_in[9];
    const float* W_out  = (const float*)d_in[10];
    const float* b_out  = (const float*)d_in[11];
    float* out = (float*)d_out;

    uint* h    = (uint*)d_ws;
    uint* qkvp = h + (size_t)MROWS * CDIM;
    uint* y    = qkvp + (size_t)MROWS * 3 * CDIM;
    short* Bqh = (short*)(y + (size_t)MROWS * CDIM);
    short* Bql = Bqh + (size_t)3 * CDIM * CDIM;
    short* Bph = Bql + (size_t)3 * CDIM * CDIM;
    short* Bpl = Bph + (size_t)CDIM * CDIM;

    const size_t need = ((size_t)MROWS * CDIM * 5) * 4 +
                        ((size_t)3 * CDIM * CDIM * 2 + (size_t)CDIM * CDIM * 2) * 2;
    const bool use_mfma = ws_size >= need;

    const dim3 blk(256);
    const int nattn = (T_SEQ / 128) * BATCH * NHEAD;  // 512 blocks, 1-D swizzled

    if (use_mfma) {
        gemm_f32_kernel<<<dim3(CDIM / 64, MROWS / 64), blk, 0, stream>>>(
            x, W_emb, b_emb, pos, (float*)h, MROWS, CDIM, VDIM, T_SEQ, 1);
        for (int l = 0; l < NLAYER; ++l) {
            wsplit_kernel<<<dim3(3 * CDIM / 64, CDIM / 16), blk, 0, stream>>>(
                Wqkv + (size_t)l * CDIM * 3 * CDIM, Bqh, Bql, 3 * CDIM, CDIM);
            gemm_mfma_kernel<<<dim3(3 * CDIM / 128, MROWS / 128), blk, 0, stream>>>(
                h, Bqh, Bql, bqkv + (size_t)l * 3 * CDIM, qkvp, MROWS, 3 * CDIM, CDIM, 1);
            attn_mfma_kernel<<<dim3(nattn), blk, 0, stream>>>(qkvp, y, 1);
            wsplit_kernel<<<dim3(CDIM / 64, CDIM / 16), blk, 0, stream>>>(
                Wproj + (size_t)l * CDIM * CDIM, Bph, Bpl, CDIM, CDIM);
            gemm_mfma_kernel<<<dim3(CDIM / 128, MROWS / 128), blk, 0, stream>>>(
                y, Bph, Bpl, bproj + (size_t)l * CDIM, h, MROWS, CDIM, CDIM, 1);
        }
        ln_kernel<<<dim3(MROWS), blk, 0, stream>>>(h, gamma, beta, (float*)y, 1);
    } else {
        gemm_f32_kernel<<<dim3(CDIM / 64, MROWS / 64), blk, 0, stream>>>(
            x, W_emb, b_emb, pos, (float*)h, MROWS, CDIM, VDIM, T_SEQ, 0);
        for (int l = 0; l < NLAYER; ++l) {
            gemm_f32_kernel<<<dim3(3 * CDIM / 64, MROWS / 64), blk, 0, stream>>>(
                (float*)h, Wqkv + (size_t)l * CDIM * 3 * CDIM, bqkv + (size_t)l * 3 * CDIM,
                nullptr, (float*)qkvp, MROWS, 3 * CDIM, CDIM, 1, 1);
            attn_mfma_kernel<<<dim3(nattn), blk, 0, stream>>>(qkvp, y, 0);
            gemm_f32_kernel<<<dim3(CDIM / 64, MROWS / 64), blk, 0, stream>>>(
                (float*)y, Wproj + (size_t)l * CDIM * CDIM, bproj + (size_t)l * CDIM,
                nullptr, (float*)h, MROWS, CDIM, CDIM, 1, 0);
        }
        ln_kernel<<<dim3(MROWS), blk, 0, stream>>>(h, gamma, beta, (float*)y, 0);
    }

    gemm_f32_kernel<<<dim3(VDIM / 64, MROWS / 64), blk, 0, stream>>>(
        (float*)y, W_out, b_out, nullptr, out, MROWS, VDIM, CDIM, 1, 0);
}

// Round 9
// 1870.910 us; speedup vs baseline: 1.2200x; 1.1871x over previous
//
#include <hip/hip_runtime.h>
#include <hip/hip_bf16.h>

#define T_SEQ 2048
#define BATCH 2
#define CDIM 1024
#define VDIM 256
#define NHEAD 16
#define DHEAD 64
#define NLAYER 8
#define MROWS (BATCH * T_SEQ) /* 4096 */

typedef __attribute__((ext_vector_type(8))) short bf16x8;
typedef __attribute__((ext_vector_type(4))) float f32x4;
typedef __attribute__((ext_vector_type(4))) int i32x4;

// v_perm_b32: sel byte 0-3 -> from 2nd arg, 4-7 -> from 1st arg
#define SELHI 0x07060302u  // top16(a)<<16 | top16(b)
#define SELLO 0x05040100u  // low16(a)<<16 | low16(b)

__device__ __forceinline__ uint prm(uint a, uint b, uint s) { return __builtin_amdgcn_perm(a, b, s); }

__device__ __forceinline__ uint bf16rne(float f) {
    uint u = __float_as_uint(f);
    return (u + 0x7fffu + ((u >> 16) & 1u)) & 0xffff0000u;
}
__device__ __forceinline__ uint packsplit(float x) {
    uint hb = bf16rne(x);
    float d = x - __uint_as_float(hb);
    uint lb = bf16rne(d);
    return prm(hb, lb, SELHI);
}
__device__ __forceinline__ float unpack2(uint u) {
    return __uint_as_float(u & 0xffff0000u) + __uint_as_float(u << 16);
}
__device__ __forceinline__ bf16x8 asb(i32x4 v) {
    union { i32x4 i; bf16x8 b; } u; u.i = v; return u.b;
}

// Frag-packed u32 activation layout for a matrix X[M][K] (K multiple of 32):
//   slot(m,k) = ((m>>4)*(K>>5) + (k>>5))*512
//             + (((k>>2)&3)*16 + (m&15))*8
//             + (k&3) + 4*((k>>4)&1)
// Lane l of a 16x16x32 MFMA A-fragment (tile mi, k-chunk kc) reads u32s
// slot_base + l*8 .. +7 (32B contiguous per lane).

// ---------------------------------------------------------------------------
// f32 GEMM (embed / final out / fallback).
// out_mode 0: f32 rows; 1: packed u32 rows; 2: frag-packed u32 (layout above).
// ---------------------------------------------------------------------------
__global__ __launch_bounds__(256) void gemm_f32_kernel(
    const float* __restrict__ A, const float* __restrict__ B,
    const float* __restrict__ bias, const float* __restrict__ addrow,
    float* __restrict__ C, int M, int N, int K, int addmod, int out_mode)
{
    __shared__ float As[16][64];
    __shared__ float Bs[16][68];

    const int tid = threadIdx.x;
    const int bn = blockIdx.x * 64;
    const int bm = blockIdx.y * 64;

    const int lrow = tid >> 2;
    const int lkq  = (tid & 3) * 4;
    const int lkr  = tid >> 4;
    const int lnq  = (tid & 15) * 4;
    const int ty   = tid >> 4;
    const int tx   = tid & 15;

    float acc[4][4];
#pragma unroll
    for (int i = 0; i < 4; ++i)
#pragma unroll
        for (int j = 0; j < 4; ++j) acc[i][j] = 0.f;

    for (int k0 = 0; k0 < K; k0 += 16) {
        __syncthreads();
        {
            float4 a4 = *(const float4*)&A[(size_t)(bm + lrow) * K + k0 + lkq];
            As[lkq + 0][lrow] = a4.x;
            As[lkq + 1][lrow] = a4.y;
            As[lkq + 2][lrow] = a4.z;
            As[lkq + 3][lrow] = a4.w;
            *(float4*)&Bs[lkr][lnq] =
                *(const float4*)&B[(size_t)(k0 + lkr) * N + bn + lnq];
        }
        __syncthreads();
#pragma unroll
        for (int kk = 0; kk < 16; ++kk) {
            const float4 a = *(const float4*)&As[kk][ty * 4];
            const float4 b = *(const float4*)&Bs[kk][tx * 4];
            acc[0][0] += a.x * b.x; acc[0][1] += a.x * b.y; acc[0][2] += a.x * b.z; acc[0][3] += a.x * b.w;
            acc[1][0] += a.y * b.x; acc[1][1] += a.y * b.y; acc[1][2] += a.y * b.z; acc[1][3] += a.y * b.w;
            acc[2][0] += a.z * b.x; acc[2][1] += a.z * b.y; acc[2][2] += a.z * b.z; acc[2][3] += a.z * b.w;
            acc[3][0] += a.w * b.x; acc[3][1] += a.w * b.y; acc[3][2] += a.w * b.z; acc[3][3] += a.w * b.w;
        }
    }

    const int ncol = bn + tx * 4;
    const float4 bv = *(const float4*)&bias[ncol];
#pragma unroll
    for (int i = 0; i < 4; ++i) {
        const int mrow = bm + ty * 4 + i;
        float4 o;
        o.x = acc[i][0] + bv.x;
        o.y = acc[i][1] + bv.y;
        o.z = acc[i][2] + bv.z;
        o.w = acc[i][3] + bv.w;
        if (addrow) {
            const float4 p = *(const float4*)&addrow[(size_t)(mrow % addmod) * N + ncol];
            o.x += p.x; o.y += p.y; o.z += p.z; o.w += p.w;
        }
        if (out_mode == 0) {
            *(float4*)&C[(size_t)mrow * N + ncol] = o;
        } else if (out_mode == 1) {
            uint4 pk;
            pk.x = packsplit(o.x); pk.y = packsplit(o.y);
            pk.z = packsplit(o.z); pk.w = packsplit(o.w);
            *(uint4*)&((uint*)C)[(size_t)mrow * N + ncol] = pk;
        } else {
            // frag-packed: 4 consecutive k (= ncol..ncol+3) -> j 0..3 of one slot
            const size_t addr = ((size_t)(mrow >> 4) * (N >> 5) + (ncol >> 5)) * 512
                              + (size_t)(((ncol >> 2) & 3) * 16 + (mrow & 15)) * 8
                              + 4 * ((ncol >> 4) & 1);
            uint4 pk;
            pk.x = packsplit(o.x); pk.y = packsplit(o.y);
            pk.z = packsplit(o.z); pk.w = packsplit(o.w);
            *(uint4*)&((uint*)C)[addr] = pk;
        }
    }
}

// ---------------------------------------------------------------------------
// Weight pre-split: W[K][N] f32 -> frag-order hi/lo bf16 arrays
// ---------------------------------------------------------------------------
__global__ __launch_bounds__(256) void wsplit_kernel(
    const float* __restrict__ W, short* __restrict__ Fh, short* __restrict__ Fl,
    int N, int K)
{
    const int ln = threadIdx.x & 63, lk = threadIdx.x >> 6;
    const int n  = blockIdx.x * 64 + ln;
    const int kq = blockIdx.y * 4 + lk;
    const int k0 = kq * 4;

    float f0 = W[(size_t)(k0 + 0) * N + n];
    float f1 = W[(size_t)(k0 + 1) * N + n];
    float f2 = W[(size_t)(k0 + 2) * N + n];
    float f3 = W[(size_t)(k0 + 3) * N + n];
    uint h0 = bf16rne(f0), h1 = bf16rne(f1), h2 = bf16rne(f2), h3 = bf16rne(f3);
    uint l0 = bf16rne(f0 - __uint_as_float(h0));
    uint l1 = bf16rne(f1 - __uint_as_float(h1));
    uint l2 = bf16rne(f2 - __uint_as_float(h2));
    uint l3 = bf16rne(f3 - __uint_as_float(h3));

    const int gl = kq & 3, j0 = ((kq >> 2) & 1) * 4;
    const size_t base = (((size_t)(n >> 4) * (K >> 5) + (kq >> 3)) * 64 + gl * 16 + (n & 15)) * 8 + j0;
    *(int2*)&Fh[base] = make_int2((int)prm(h1, h0, SELHI), (int)prm(h3, h2, SELHI));
    *(int2*)&Fl[base] = make_int2((int)prm(l1, l0, SELHI), (int)prm(l3, l2, SELHI));
}

// ---------------------------------------------------------------------------
// MFMA bf16x2 GEMM, LDS-FREE: A is frag-packed u32 in global, B pre-split
// frag-order bf16 in global. Each lane loads its own fragments (coalesced),
// splits A hi/lo via v_perm in-register. No barriers; waves self-pipeline.
// 128x128 tile, BK=32, 4 waves (2x2), 48 MFMA / K-step.
// out_mode 1: row-major packed u32. out_mode 2: frag-packed u32 (K2 = N).
// ---------------------------------------------------------------------------
__global__ __launch_bounds__(256) void gemm_mfma_kernel(
    const uint* __restrict__ Apf, const short* __restrict__ Bhf,
    const short* __restrict__ Blf, const float* __restrict__ bias,
    void* __restrict__ Cv, int M, int N, int K, int out_mode)
{
    const int tid = threadIdx.x, lane = tid & 63, w = tid >> 6;
    const int wr = w >> 1, wc = w & 1, x = lane & 15, gl = lane >> 4;
    const int bm = blockIdx.y * 128, bn = blockIdx.x * 128;
    const int nkc = K >> 5;

    // lane-resolved fragment base pointers (tile stride = nkc*512 elems)
    const uint*  ab = Apf + ((size_t)((bm >> 4) + wr * 4) * nkc) * 512 + (size_t)lane * 8;
    const short* hb = Bhf + (((size_t)((bn >> 4) + wc * 4) * nkc) * 64 + lane) * 8;
    const short* lb = Blf + (((size_t)((bn >> 4) + wc * 4) * nkc) * 64 + lane) * 8;
    const size_t tstrA = (size_t)nkc * 512;   // u32s per A tile-row
    const size_t tstrB = (size_t)nkc * 512;   // shorts per B tile-row

    f32x4 acc[4][4];
#pragma unroll
    for (int mi = 0; mi < 4; ++mi)
#pragma unroll
        for (int ni = 0; ni < 4; ++ni) acc[mi][ni] = (f32x4){0.f, 0.f, 0.f, 0.f};

    for (int kc = 0; kc < nkc; ++kc) {
        const size_t ko = (size_t)kc * 512;
        bf16x8 ah[4], al[4], bh[4], bl[4];
#pragma unroll
        for (int t = 0; t < 4; ++t) {
            const uint* ap = ab + t * tstrA + ko;
            uint4 a0 = *(const uint4*)ap;
            uint4 a1 = *(const uint4*)(ap + 4);
            i32x4 h4, l4;
            h4[0] = (int)prm(a0.y, a0.x, SELHI); h4[1] = (int)prm(a0.w, a0.z, SELHI);
            h4[2] = (int)prm(a1.y, a1.x, SELHI); h4[3] = (int)prm(a1.w, a1.z, SELHI);
            l4[0] = (int)prm(a0.y, a0.x, SELLO); l4[1] = (int)prm(a0.w, a0.z, SELLO);
            l4[2] = (int)prm(a1.y, a1.x, SELLO); l4[3] = (int)prm(a1.w, a1.z, SELLO);
            ah[t] = asb(h4); al[t] = asb(l4);
            bh[t] = *(const bf16x8*)(hb + t * tstrB + ko);
            bl[t] = *(const bf16x8*)(lb + t * tstrB + ko);
        }
        __builtin_amdgcn_s_setprio(1);
#pragma unroll
        for (int mi = 0; mi < 4; ++mi)
#pragma unroll
            for (int ni = 0; ni < 4; ++ni) {
                acc[mi][ni] = __builtin_amdgcn_mfma_f32_16x16x32_bf16(ah[mi], bh[ni], acc[mi][ni], 0, 0, 0);
                acc[mi][ni] = __builtin_amdgcn_mfma_f32_16x16x32_bf16(ah[mi], bl[ni], acc[mi][ni], 0, 0, 0);
                acc[mi][ni] = __builtin_amdgcn_mfma_f32_16x16x32_bf16(al[mi], bh[ni], acc[mi][ni], 0, 0, 0);
            }
        __builtin_amdgcn_s_setprio(0);
    }

#pragma unroll
    for (int ni = 0; ni < 4; ++ni) {
        const int n = bn + wc * 64 + ni * 16 + x;
        const float bv = bias[n];
#pragma unroll
        for (int mi = 0; mi < 4; ++mi) {
            const f32x4 o = acc[mi][ni];
            if (out_mode == 1) {
                const int m0 = bm + wr * 64 + mi * 16 + gl * 4;
                uint* C = (uint*)Cv;
                C[(size_t)(m0 + 0) * N + n] = packsplit(o[0] + bv);
                C[(size_t)(m0 + 1) * N + n] = packsplit(o[1] + bv);
                C[(size_t)(m0 + 2) * N + n] = packsplit(o[2] + bv);
                C[(size_t)(m0 + 3) * N + n] = packsplit(o[3] + bv);
            } else {
                // frag-packed for consumer with K2 = N
                uint* C = (uint*)Cv;
                const size_t mt = (size_t)(bm >> 4) + wr * 4 + mi;
                const size_t base = (mt * (N >> 5) + (n >> 5)) * 512
                                  + (size_t)(((n >> 2) & 3) * 16 + gl * 4) * 8
                                  + (n & 3) + 4 * ((n >> 4) & 1);
                C[base + 0 * 8] = packsplit(o[0] + bv);
                C[base + 1 * 8] = packsplit(o[1] + bv);
                C[base + 2 * 8] = packsplit(o[2] + bv);
                C[base + 3 * 8] = packsplit(o[3] + bv);
            }
        }
    }
}

// ---------------------------------------------------------------------------
// Flash attention MFMA. QBLK=128, QK^T 1-term, PV 2-term, XCD swizzle,
// register prefetch, setprio. opack 0: f32 rows; 1: frag-packed u32.
// ---------------------------------------------------------------------------
__global__ __launch_bounds__(256) void attn_mfma_kernel(
    const uint* __restrict__ qkv, void* __restrict__ y, int opack)
{
    __shared__ __align__(16) short khi[4][2][64][8];
    __shared__ __align__(16) short vhi[4][2][64][8];
    __shared__ uint vpl[64][68];

    const int tid  = threadIdx.x;
    const int w    = tid >> 6;
    const int lane = tid & 63;
    const int x    = lane & 15;
    const int gl   = lane >> 4;

    const int orig = blockIdx.x;
    const int wgid = (orig & 7) * 64 + (orig >> 3);
    const int bh = wgid >> 4;
    const int b = bh >> 4, hh = bh & 15;
    const int t0 = (wgid & 15) * 128;

    i32x4 qhi[2][2];
#pragma unroll
    for (int qf = 0; qf < 2; ++qf) {
        const uint* qp = qkv + (size_t)(b * T_SEQ + t0 + 64 * qf + 16 * w + x) * 3072 + hh * 64;
#pragma unroll
        for (int ch = 0; ch < 2; ++ch) {
            uint4 a0 = *(const uint4*)(qp + 32 * ch + 4 * gl);
            uint4 a1 = *(const uint4*)(qp + 32 * ch + 16 + 4 * gl);
            qhi[qf][ch][0] = (int)prm(a0.y, a0.x, SELHI); qhi[qf][ch][1] = (int)prm(a0.w, a0.z, SELHI);
            qhi[qf][ch][2] = (int)prm(a1.y, a1.x, SELHI); qhi[qf][ch][3] = (int)prm(a1.w, a1.z, SELHI);
        }
    }

    const int rK = tid >> 2, q4 = tid & 3;
    const int sc_s = rK >> 4, xk = rK & 15, chS = q4 >> 1, h2 = q4 & 1;

    const uint* kbase = qkv + (size_t)b * T_SEQ * 3072 + (size_t)rK * 3072 + 1024 + hh * 64 + 16 * q4;
    const uint* vbase = kbase + 1024;

    f32x4 oacc[2][4];
#pragma unroll
    for (int qf = 0; qf < 2; ++qf)
#pragma unroll
        for (int i = 0; i < 4; ++i) oacc[qf][i] = (f32x4){0.f, 0.f, 0.f, 0.f};
    float lsum[2] = {0.f, 0.f};

    uint4 kreg[4], vreg[4];
#pragma unroll
    for (int i = 0; i < 4; ++i) {
        kreg[i] = ((const uint4*)kbase)[i];
        vreg[i] = ((const uint4*)vbase)[i];
    }

    for (int s0 = 0; s0 < T_SEQ; s0 += 64) {
        {
            uint uu[16] = {kreg[0].x, kreg[0].y, kreg[0].z, kreg[0].w,
                           kreg[1].x, kreg[1].y, kreg[1].z, kreg[1].w,
                           kreg[2].x, kreg[2].y, kreg[2].z, kreg[2].w,
                           kreg[3].x, kreg[3].y, kreg[3].z, kreg[3].w};
#pragma unroll
            for (int g = 0; g < 4; ++g) {
                int2 hi2;
                hi2.x = (int)prm(uu[4 * g + 1], uu[4 * g + 0], SELHI);
                hi2.y = (int)prm(uu[4 * g + 3], uu[4 * g + 2], SELHI);
                *(int2*)&khi[sc_s][chS][16 * g + xk][4 * h2] = hi2;
            }
            *(uint4*)&vpl[rK][16 * q4 + 0]  = vreg[0];
            *(uint4*)&vpl[rK][16 * q4 + 4]  = vreg[1];
            *(uint4*)&vpl[rK][16 * q4 + 8]  = vreg[2];
            *(uint4*)&vpl[rK][16 * q4 + 12] = vreg[3];
        }
        __syncthreads();

        if (s0 + 64 < T_SEQ) {
            const uint* kp = kbase + (size_t)(s0 + 64) * 3072;
            const uint* vp = vbase + (size_t)(s0 + 64) * 3072;
#pragma unroll
            for (int i = 0; i < 4; ++i) {
                kreg[i] = ((const uint4*)kp)[i];
                vreg[i] = ((const uint4*)vp)[i];
            }
        }

        f32x4 s4[2][4];
#pragma unroll
        for (int qf = 0; qf < 2; ++qf)
#pragma unroll
            for (int sc = 0; sc < 4; ++sc) s4[qf][sc] = (f32x4){0.f, 0.f, 0.f, 0.f};
        __builtin_amdgcn_s_setprio(1);
#pragma unroll
        for (int sc = 0; sc < 4; ++sc) {
#pragma unroll
            for (int ch = 0; ch < 2; ++ch) {
                bf16x8 kh = *(const bf16x8*)&khi[sc][ch][lane][0];
                s4[0][sc] = __builtin_amdgcn_mfma_f32_16x16x32_bf16(kh, asb(qhi[0][ch]), s4[0][sc], 0, 0, 0);
                s4[1][sc] = __builtin_amdgcn_mfma_f32_16x16x32_bf16(kh, asb(qhi[1][ch]), s4[1][sc], 0, 0, 0);
            }
        }
        __builtin_amdgcn_s_setprio(0);

#pragma unroll
        for (int t2 = 0; t2 < 2; ++t2) {
            const int G = tid + 256 * t2;
            const int lt = G & 63, chv = (G >> 6) & 1, dm = G >> 7;
            const int glt = lt >> 4, xt = lt & 15, col = 16 * dm + xt;
            uint v0 = vpl[32 * chv + 4 * glt + 0][col];
            uint v1 = vpl[32 * chv + 4 * glt + 1][col];
            uint v2 = vpl[32 * chv + 4 * glt + 2][col];
            uint v3 = vpl[32 * chv + 4 * glt + 3][col];
            uint v4 = vpl[32 * chv + 4 * glt + 16][col];
            uint v5 = vpl[32 * chv + 4 * glt + 17][col];
            uint v6 = vpl[32 * chv + 4 * glt + 18][col];
            uint v7 = vpl[32 * chv + 4 * glt + 19][col];
            i32x4 hi4;
            hi4[0] = (int)prm(v1, v0, SELHI); hi4[1] = (int)prm(v3, v2, SELHI);
            hi4[2] = (int)prm(v5, v4, SELHI); hi4[3] = (int)prm(v7, v6, SELHI);
            *(i32x4*)&vhi[dm][chv][lt][0] = hi4;
        }

        i32x4 pfh[2][2], pfl[2][2];
#pragma unroll
        for (int qf = 0; qf < 2; ++qf) {
            f32x4 pc[4];
#pragma unroll
            for (int sc = 0; sc < 4; ++sc) {
                pc[sc][0] = __expf(s4[qf][sc][0] * 0.125f);
                pc[sc][1] = __expf(s4[qf][sc][1] * 0.125f);
                pc[sc][2] = __expf(s4[qf][sc][2] * 0.125f);
                pc[sc][3] = __expf(s4[qf][sc][3] * 0.125f);
                lsum[qf] += pc[sc][0] + pc[sc][1] + pc[sc][2] + pc[sc][3];
            }
#pragma unroll
            for (int c = 0; c < 2; ++c) {
                f32x4 pa = pc[2 * c], pb = pc[2 * c + 1];
                uint a0 = __float_as_uint(pa[0]), a1 = __float_as_uint(pa[1]);
                uint a2 = __float_as_uint(pa[2]), a3 = __float_as_uint(pa[3]);
                uint b0 = __float_as_uint(pb[0]), b1 = __float_as_uint(pb[1]);
                uint b2 = __float_as_uint(pb[2]), b3 = __float_as_uint(pb[3]);
                pfh[qf][c][0] = (int)prm(a1, a0, SELHI); pfh[qf][c][1] = (int)prm(a3, a2, SELHI);
                pfh[qf][c][2] = (int)prm(b1, b0, SELHI); pfh[qf][c][3] = (int)prm(b3, b2, SELHI);
                float d0 = pa[0] - __uint_as_float(a0 & 0xffff0000u);
                float d1 = pa[1] - __uint_as_float(a1 & 0xffff0000u);
                float d2 = pa[2] - __uint_as_float(a2 & 0xffff0000u);
                float d3 = pa[3] - __uint_as_float(a3 & 0xffff0000u);
                float e0 = pb[0] - __uint_as_float(b0 & 0xffff0000u);
                float e1 = pb[1] - __uint_as_float(b1 & 0xffff0000u);
                float e2 = pb[2] - __uint_as_float(b2 & 0xffff0000u);
                float e3 = pb[3] - __uint_as_float(b3 & 0xffff0000u);
                pfl[qf][c][0] = (int)prm(__float_as_uint(d1), __float_as_uint(d0), SELHI);
                pfl[qf][c][1] = (int)prm(__float_as_uint(d3), __float_as_uint(d2), SELHI);
                pfl[qf][c][2] = (int)prm(__float_as_uint(e1), __float_as_uint(e0), SELHI);
                pfl[qf][c][3] = (int)prm(__float_as_uint(e3), __float_as_uint(e2), SELHI);
            }
        }
        __syncthreads();

        __builtin_amdgcn_s_setprio(1);
#pragma unroll
        for (int dm = 0; dm < 4; ++dm) {
#pragma unroll
            for (int ch = 0; ch < 2; ++ch) {
                bf16x8 vh = *(const bf16x8*)&vhi[dm][ch][lane][0];
#pragma unroll
                for (int qf = 0; qf < 2; ++qf) {
                    oacc[qf][dm] = __builtin_amdgcn_mfma_f32_16x16x32_bf16(vh, asb(pfh[qf][ch]), oacc[qf][dm], 0, 0, 0);
                    oacc[qf][dm] = __builtin_amdgcn_mfma_f32_16x16x32_bf16(vh, asb(pfl[qf][ch]), oacc[qf][dm], 0, 0, 0);
                }
            }
        }
        __builtin_amdgcn_s_setprio(0);
    }

#pragma unroll
    for (int qf = 0; qf < 2; ++qf) {
        float ls = lsum[qf];
        ls += __shfl_xor(ls, 16);
        ls += __shfl_xor(ls, 32);
        const float invl = 1.f / ls;
        if (opack) {
            // frag-packed u32 (consumer K2 = CDIM): row mt, k-tile = hh*2 + dm>>1
            uint* yp = (uint*)y;
            const size_t mt = (size_t)((b * T_SEQ + t0) >> 4) + 4 * qf + w;
#pragma unroll
            for (int dm = 0; dm < 4; ++dm) {
                f32x4 o = oacc[qf][dm];
                const size_t addr = (mt * 32 + hh * 2 + (dm >> 1)) * 512
                                  + (size_t)lane * 8 + 4 * (dm & 1);
                uint4 pk;
                pk.x = packsplit(o[0] * invl); pk.y = packsplit(o[1] * invl);
                pk.z = packsplit(o[2] * invl); pk.w = packsplit(o[3] * invl);
                *(uint4*)&yp[addr] = pk;
            }
        } else {
            float* yp = (float*)y + (size_t)(b * T_SEQ + t0 + 64 * qf + 16 * w + x) * CDIM + hh * 64;
#pragma unroll
            for (int dm = 0; dm < 4; ++dm) {
                f32x4 o = oacc[qf][dm];
                o[0] *= invl; o[1] *= invl; o[2] *= invl; o[3] *= invl;
                *(f32x4*)(yp + 16 * dm + 4 * gl) = o;
            }
        }
    }
}

// ---------------------------------------------------------------------------
// LayerNorm; input: 0 = f32 rows, 2 = frag-packed u32.
// ---------------------------------------------------------------------------
__global__ __launch_bounds__(256) void ln_kernel(
    const void* __restrict__ h, const float* __restrict__ gamma,
    const float* __restrict__ beta, float* __restrict__ out, int packed)
{
    const int row = blockIdx.x;
    const int tid = threadIdx.x;

    float4 v;
    if (packed == 2) {
        const size_t addr = ((size_t)(row >> 4) * 32 + (tid >> 3)) * 512
                          + (size_t)((tid & 3) * 16 + (row & 15)) * 8
                          + 4 * ((tid >> 2) & 1);
        uint4 u = *(const uint4*)&((const uint*)h)[addr];
        v.x = unpack2(u.x); v.y = unpack2(u.y); v.z = unpack2(u.z); v.w = unpack2(u.w);
    } else {
        v = *(const float4*)&((const float*)h)[(size_t)row * CDIM + tid * 4];
    }
    float s  = v.x + v.y + v.z + v.w;
    float ss = v.x * v.x + v.y * v.y + v.z * v.z + v.w * v.w;
#pragma unroll
    for (int off = 1; off < 64; off <<= 1) {
        s  += __shfl_xor(s, off);
        ss += __shfl_xor(ss, off);
    }
    __shared__ float rs[4], rss[4];
    const int wid = tid >> 6;
    if ((tid & 63) == 0) { rs[wid] = s; rss[wid] = ss; }
    __syncthreads();
    s  = rs[0] + rs[1] + rs[2] + rs[3];
    ss = rss[0] + rss[1] + rss[2] + rss[3];

    const float mu   = s * (1.f / (float)CDIM);
    const float var  = ss * (1.f / (float)CDIM) - mu * mu;
    const float rstd = rsqrtf(var + 1e-5f);

    const float4 g  = *(const float4*)&gamma[tid * 4];
    const float4 be = *(const float4*)&beta[tid * 4];
    float4 o;
    o.x = (v.x - mu) * rstd * g.x + be.x;
    o.y = (v.y - mu) * rstd * g.y + be.y;
    o.z = (v.z - mu) * rstd * g.z + be.z;
    o.w = (v.w - mu) * rstd * g.w + be.w;
    *(float4*)&out[(size_t)row * CDIM + tid * 4] = o;
}

// ---------------------------------------------------------------------------
extern "C" void kernel_launch(void* const* d_in, const int* in_sizes, int n_in,
                              void* d_out, int out_size, void* d_ws, size_t ws_size,
                              hipStream_t stream)
{
    const float* x      = (const float*)d_in[0];
    const float* W_emb  = (const float*)d_in[1];
    const float* b_emb  = (const float*)d_in[2];
    const float* pos    = (const float*)d_in[3];
    const float* Wqkv   = (const float*)d_in[4];
    const float* bqkv   = (const float*)d_in[5];
    const float* Wproj  = (const float*)d_in[6];
    const float* bproj  = (const float*)d_in[7];
    const float* gamma  = (const float*)d_in[8];
    const float* beta   = (const float*)d_in[9];
    const float* W_out  = (const float*)d_in[10];
    const float* b_out  = (const float*)d_in[11];
    float* out = (float*)d_out;

    uint* h    = (uint*)d_ws;                      // frag-packed u32 (or f32 fallback)
    uint* qkvp = h + (size_t)MROWS * CDIM;         // row-major packed u32
    uint* y    = qkvp + (size_t)MROWS * 3 * CDIM;  // frag-packed u32; reused as f32 by ln
    short* Bqh = (short*)(y + (size_t)MROWS * CDIM);
    short* Bql = Bqh + (size_t)3 * CDIM * CDIM;
    short* Bph = Bql + (size_t)3 * CDIM * CDIM;
    short* Bpl = Bph + (size_t)CDIM * CDIM;

    const size_t need = ((size_t)MROWS * CDIM * 5) * 4 +
                        ((size_t)3 * CDIM * CDIM * 2 + (size_t)CDIM * CDIM * 2) * 2;
    const bool use_mfma = ws_size >= need;

    const dim3 blk(256);
    const int nattn = (T_SEQ / 128) * BATCH * NHEAD;  // 512 blocks, 1-D swizzled

    if (use_mfma) {
        // h(frag) = x @ W_emb + b_emb + pos
        gemm_f32_kernel<<<dim3(CDIM / 64, MROWS / 64), blk, 0, stream>>>(
            x, W_emb, b_emb, pos, (float*)h, MROWS, CDIM, VDIM, T_SEQ, 2);
        for (int l = 0; l < NLAYER; ++l) {
            wsplit_kernel<<<dim3(3 * CDIM / 64, CDIM / 16), blk, 0, stream>>>(
                Wqkv + (size_t)l * CDIM * 3 * CDIM, Bqh, Bql, 3 * CDIM, CDIM);
            gemm_mfma_kernel<<<dim3(3 * CDIM / 128, MROWS / 128), blk, 0, stream>>>(
                h, Bqh, Bql, bqkv + (size_t)l * 3 * CDIM, qkvp, MROWS, 3 * CDIM, CDIM, 1);
            attn_mfma_kernel<<<dim3(nattn), blk, 0, stream>>>(qkvp, y, 1);
            wsplit_kernel<<<dim3(CDIM / 64, CDIM / 16), blk, 0, stream>>>(
                Wproj + (size_t)l * CDIM * CDIM, Bph, Bpl, CDIM, CDIM);
            gemm_mfma_kernel<<<dim3(CDIM / 128, MROWS / 128), blk, 0, stream>>>(
                y, Bph, Bpl, bproj + (size_t)l * CDIM, h, MROWS, CDIM, CDIM, 2);
        }
        ln_kernel<<<dim3(MROWS), blk, 0, stream>>>(h, gamma, beta, (float*)y, 2);
    } else {
        gemm_f32_kernel<<<dim3(CDIM / 64, MROWS / 64), blk, 0, stream>>>(
            x, W_emb, b_emb, pos, (float*)h, MROWS, CDIM, VDIM, T_SEQ, 0);
        for (int l = 0; l < NLAYER; ++l) {
            gemm_f32_kernel<<<dim3(3 * CDIM / 64, MROWS / 64), blk, 0, stream>>>(
                (float*)h, Wqkv + (size_t)l * CDIM * 3 * CDIM, bqkv + (size_t)l * 3 * CDIM,
                nullptr, (float*)qkvp, MROWS, 3 * CDIM, CDIM, 1, 1);
            attn_mfma_kernel<<<dim3(nattn), blk, 0, stream>>>(qkvp, y, 0);
            gemm_f32_kernel<<<dim3(CDIM / 64, MROWS / 64), blk, 0, stream>>>(
                (float*)y, Wproj + (size_t)l * CDIM * CDIM, bproj + (size_t)l * CDIM,
                nullptr, (float*)h, MROWS, CDIM, CDIM, 1, 0);
        }
        ln_kernel<<<dim3(MROWS), blk, 0, stream>>>(h, gamma, beta, (float*)y, 0);
    }

    gemm_f32_kernel<<<dim3(VDIM / 64, MROWS / 64), blk, 0, stream>>>(
        (float*)y, W_out, b_out, nullptr, out, MROWS, VDIM, CDIM, 1, 0);
}

// Round 10
// 1594.878 us; speedup vs baseline: 1.4312x; 1.1731x over previous
//
#include <hip/hip_runtime.h>
#include <hip/hip_bf16.h>

#define T_SEQ 2048
#define BATCH 2
#define CDIM 1024
#define VDIM 256
#define NHEAD 16
#define DHEAD 64
#define NLAYER 8
#define MROWS (BATCH * T_SEQ) /* 4096 */

typedef __attribute__((ext_vector_type(8))) short bf16x8;
typedef __attribute__((ext_vector_type(4))) float f32x4;
typedef __attribute__((ext_vector_type(4))) int i32x4;

#define SELHI 0x07060302u
#define SELLO 0x05040100u

__device__ __forceinline__ uint prm(uint a, uint b, uint s) { return __builtin_amdgcn_perm(a, b, s); }

__device__ __forceinline__ uint bf16rne(float f) {
    uint u = __float_as_uint(f);
    return (u + 0x7fffu + ((u >> 16) & 1u)) & 0xffff0000u;
}
__device__ __forceinline__ uint packsplit(float x) {
    uint hb = bf16rne(x);
    float d = x - __uint_as_float(hb);
    uint lb = bf16rne(d);
    return prm(hb, lb, SELHI);
}
__device__ __forceinline__ float unpack2(uint u) {
    return __uint_as_float(u & 0xffff0000u) + __uint_as_float(u << 16);
}
__device__ __forceinline__ bf16x8 asb(i32x4 v) {
    union { i32x4 i; bf16x8 b; } u; u.i = v; return u.b;
}
__device__ __forceinline__ short bfs(float f) { return (short)(bf16rne(f) >> 16); }

// Frag-packed u32 activation layout for X[M][K] (K mult of 32):
//   slot(m,k) = ((m>>4)*(K>>5)+(k>>5))*512 + (((k>>2)&3)*16+(m&15))*8 + (k&3)+4*((k>>4)&1)

// ---------------------------------------------------------------------------
// f32 GEMM (embed / final out). out_mode 0: f32 rows; 2: frag-packed u32.
// ---------------------------------------------------------------------------
__global__ __launch_bounds__(256) void gemm_f32_kernel(
    const float* __restrict__ A, const float* __restrict__ B,
    const float* __restrict__ bias, const float* __restrict__ addrow,
    float* __restrict__ C, int M, int N, int K, int addmod, int out_mode)
{
    __shared__ float As[16][64];
    __shared__ float Bs[16][68];

    const int tid = threadIdx.x;
    const int bn = blockIdx.x * 64;
    const int bm = blockIdx.y * 64;

    const int lrow = tid >> 2;
    const int lkq  = (tid & 3) * 4;
    const int lkr  = tid >> 4;
    const int lnq  = (tid & 15) * 4;
    const int ty   = tid >> 4;
    const int tx   = tid & 15;

    float acc[4][4];
#pragma unroll
    for (int i = 0; i < 4; ++i)
#pragma unroll
        for (int j = 0; j < 4; ++j) acc[i][j] = 0.f;

    for (int k0 = 0; k0 < K; k0 += 16) {
        __syncthreads();
        {
            float4 a4 = *(const float4*)&A[(size_t)(bm + lrow) * K + k0 + lkq];
            As[lkq + 0][lrow] = a4.x;
            As[lkq + 1][lrow] = a4.y;
            As[lkq + 2][lrow] = a4.z;
            As[lkq + 3][lrow] = a4.w;
            *(float4*)&Bs[lkr][lnq] =
                *(const float4*)&B[(size_t)(k0 + lkr) * N + bn + lnq];
        }
        __syncthreads();
#pragma unroll
        for (int kk = 0; kk < 16; ++kk) {
            const float4 a = *(const float4*)&As[kk][ty * 4];
            const float4 b = *(const float4*)&Bs[kk][tx * 4];
            acc[0][0] += a.x * b.x; acc[0][1] += a.x * b.y; acc[0][2] += a.x * b.z; acc[0][3] += a.x * b.w;
            acc[1][0] += a.y * b.x; acc[1][1] += a.y * b.y; acc[1][2] += a.y * b.z; acc[1][3] += a.y * b.w;
            acc[2][0] += a.z * b.x; acc[2][1] += a.z * b.y; acc[2][2] += a.z * b.z; acc[2][3] += a.z * b.w;
            acc[3][0] += a.w * b.x; acc[3][1] += a.w * b.y; acc[3][2] += a.w * b.z; acc[3][3] += a.w * b.w;
        }
    }

    const int ncol = bn + tx * 4;
    const float4 bv = *(const float4*)&bias[ncol];
#pragma unroll
    for (int i = 0; i < 4; ++i) {
        const int mrow = bm + ty * 4 + i;
        float4 o;
        o.x = acc[i][0] + bv.x;
        o.y = acc[i][1] + bv.y;
        o.z = acc[i][2] + bv.z;
        o.w = acc[i][3] + bv.w;
        if (addrow) {
            const float4 p = *(const float4*)&addrow[(size_t)(mrow % addmod) * N + ncol];
            o.x += p.x; o.y += p.y; o.z += p.z; o.w += p.w;
        }
        if (out_mode == 0) {
            *(float4*)&C[(size_t)mrow * N + ncol] = o;
        } else {
            const size_t addr = ((size_t)(mrow >> 4) * (N >> 5) + (ncol >> 5)) * 512
                              + (size_t)(((ncol >> 2) & 3) * 16 + (mrow & 15)) * 8
                              + 4 * ((ncol >> 4) & 1);
            uint4 pk;
            pk.x = packsplit(o.x); pk.y = packsplit(o.y);
            pk.z = packsplit(o.z); pk.w = packsplit(o.w);
            *(uint4*)&((uint*)C)[addr] = pk;
        }
    }
}

// ---------------------------------------------------------------------------
// Weight pre-split: W[K][N] f32 -> frag-order hi/lo bf16 arrays
// ---------------------------------------------------------------------------
__global__ __launch_bounds__(256) void wsplit_kernel(
    const float* __restrict__ W, short* __restrict__ Fh, short* __restrict__ Fl,
    int N, int K)
{
    const int ln = threadIdx.x & 63, lk = threadIdx.x >> 6;
    const int n  = blockIdx.x * 64 + ln;
    const int kq = blockIdx.y * 4 + lk;
    const int k0 = kq * 4;

    float f0 = W[(size_t)(k0 + 0) * N + n];
    float f1 = W[(size_t)(k0 + 1) * N + n];
    float f2 = W[(size_t)(k0 + 2) * N + n];
    float f3 = W[(size_t)(k0 + 3) * N + n];
    uint h0 = bf16rne(f0), h1 = bf16rne(f1), h2 = bf16rne(f2), h3 = bf16rne(f3);
    uint l0 = bf16rne(f0 - __uint_as_float(h0));
    uint l1 = bf16rne(f1 - __uint_as_float(h1));
    uint l2 = bf16rne(f2 - __uint_as_float(h2));
    uint l3 = bf16rne(f3 - __uint_as_float(h3));

    const int gl = kq & 3, j0 = ((kq >> 2) & 1) * 4;
    const size_t base = (((size_t)(n >> 4) * (K >> 5) + (kq >> 3)) * 64 + gl * 16 + (n & 15)) * 8 + j0;
    *(int2*)&Fh[base] = make_int2((int)prm(h1, h0, SELHI), (int)prm(h3, h2, SELHI));
    *(int2*)&Fl[base] = make_int2((int)prm(l1, l0, SELHI), (int)prm(l3, l2, SELHI));
}

// ---------------------------------------------------------------------------
// MFMA bf16x2 GEMM, LDS-free (validated round 9). out_mode:
//   2: frag-packed u32 into Cv (consumer K2 = N)
//   3: qkv split -> Cq row-major packed u32 [m][1024] (n<1024),
//      Ckf K-hi bf16 frags [bh][s/16][d/32][lane][8] (1024<=n<2048),
//      Cvf V^T-hi bf16 frags [bh][s/32][d/16][lane][8] (n>=2048).
// ---------------------------------------------------------------------------
__global__ __launch_bounds__(256) void gemm_mfma_kernel(
    const uint* __restrict__ Apf, const short* __restrict__ Bhf,
    const short* __restrict__ Blf, const float* __restrict__ bias,
    uint* __restrict__ Cv, uint* __restrict__ Cq, short* __restrict__ Ckf,
    short* __restrict__ Cvf, int M, int N, int K, int out_mode)
{
    const int tid = threadIdx.x, lane = tid & 63, w = tid >> 6;
    const int wr = w >> 1, wc = w & 1, x = lane & 15, gl = lane >> 4;
    const int bm = blockIdx.y * 128, bn = blockIdx.x * 128;
    const int nkc = K >> 5;

    const uint*  ab = Apf + ((size_t)((bm >> 4) + wr * 4) * nkc) * 512 + (size_t)lane * 8;
    const short* hb = Bhf + (((size_t)((bn >> 4) + wc * 4) * nkc) * 64 + lane) * 8;
    const short* lb = Blf + (((size_t)((bn >> 4) + wc * 4) * nkc) * 64 + lane) * 8;
    const size_t tstr = (size_t)nkc * 512;

    f32x4 acc[4][4];
#pragma unroll
    for (int mi = 0; mi < 4; ++mi)
#pragma unroll
        for (int ni = 0; ni < 4; ++ni) acc[mi][ni] = (f32x4){0.f, 0.f, 0.f, 0.f};

    for (int kc = 0; kc < nkc; ++kc) {
        const size_t ko = (size_t)kc * 512;
        bf16x8 ah[4], al[4], bh[4], bl[4];
#pragma unroll
        for (int t = 0; t < 4; ++t) {
            const uint* ap = ab + t * tstr + ko;
            uint4 a0 = *(const uint4*)ap;
            uint4 a1 = *(const uint4*)(ap + 4);
            i32x4 h4, l4;
            h4[0] = (int)prm(a0.y, a0.x, SELHI); h4[1] = (int)prm(a0.w, a0.z, SELHI);
            h4[2] = (int)prm(a1.y, a1.x, SELHI); h4[3] = (int)prm(a1.w, a1.z, SELHI);
            l4[0] = (int)prm(a0.y, a0.x, SELLO); l4[1] = (int)prm(a0.w, a0.z, SELLO);
            l4[2] = (int)prm(a1.y, a1.x, SELLO); l4[3] = (int)prm(a1.w, a1.z, SELLO);
            ah[t] = asb(h4); al[t] = asb(l4);
            bh[t] = *(const bf16x8*)(hb + t * tstr + ko);
            bl[t] = *(const bf16x8*)(lb + t * tstr + ko);
        }
        __builtin_amdgcn_s_setprio(1);
#pragma unroll
        for (int mi = 0; mi < 4; ++mi)
#pragma unroll
            for (int ni = 0; ni < 4; ++ni) {
                acc[mi][ni] = __builtin_amdgcn_mfma_f32_16x16x32_bf16(ah[mi], bh[ni], acc[mi][ni], 0, 0, 0);
                acc[mi][ni] = __builtin_amdgcn_mfma_f32_16x16x32_bf16(ah[mi], bl[ni], acc[mi][ni], 0, 0, 0);
                acc[mi][ni] = __builtin_amdgcn_mfma_f32_16x16x32_bf16(al[mi], bh[ni], acc[mi][ni], 0, 0, 0);
            }
        __builtin_amdgcn_s_setprio(0);
    }

#pragma unroll
    for (int ni = 0; ni < 4; ++ni) {
        const int n = bn + wc * 64 + ni * 16 + x;
        const float bv = bias[n];
#pragma unroll
        for (int mi = 0; mi < 4; ++mi) {
            const int m0 = bm + wr * 64 + mi * 16 + gl * 4;
            const f32x4 o = acc[mi][ni];
            if (out_mode == 2) {
                const size_t mt = (size_t)(bm >> 4) + wr * 4 + mi;
                const size_t base = (mt * (N >> 5) + (n >> 5)) * 512
                                  + (size_t)(((n >> 2) & 3) * 16 + gl * 4) * 8
                                  + (n & 3) + 4 * ((n >> 4) & 1);
                Cv[base + 0 * 8] = packsplit(o[0] + bv);
                Cv[base + 1 * 8] = packsplit(o[1] + bv);
                Cv[base + 2 * 8] = packsplit(o[2] + bv);
                Cv[base + 3 * 8] = packsplit(o[3] + bv);
            } else if (n < 1024) {
                // Q: row-major packed u32, stride 1024
                Cq[(size_t)(m0 + 0) * 1024 + n] = packsplit(o[0] + bv);
                Cq[(size_t)(m0 + 1) * 1024 + n] = packsplit(o[1] + bv);
                Cq[(size_t)(m0 + 2) * 1024 + n] = packsplit(o[2] + bv);
                Cq[(size_t)(m0 + 3) * 1024 + n] = packsplit(o[3] + bv);
            } else if (n < 2048) {
                // K-hi frag: lane=(s&15)+16*((dd&15)>>2), j=(dd&3)+4*(dd>>4)
                const int dd6 = n - 1024;
                const int hhh = dd6 >> 6, ch = (dd6 >> 5) & 1, dd = dd6 & 31;
                const int bq = m0 >> 11, sv = m0 & (T_SEQ - 1);
                const size_t base = ((((size_t)(bq * NHEAD + hhh) * 128 + (sv >> 4)) * 2 + ch) * 64
                                    + 16 * ((dd & 15) >> 2) + (sv & 15)) * 8
                                    + (dd & 3) + 4 * (dd >> 4);
                Ckf[base + 0]  = bfs(o[0] + bv);
                Ckf[base + 8]  = bfs(o[1] + bv);
                Ckf[base + 16] = bfs(o[2] + bv);
                Ckf[base + 24] = bfs(o[3] + bv);
            } else {
                // V^T-hi frag: lane=xt+16*((sv&15)>>2), j=(sv&3)+4*((sv>>4)&1)
                const int dd6 = n - 2048;
                const int hhh = dd6 >> 6, dmi = (dd6 >> 4) & 3, xt = dd6 & 15;
                const int bq = m0 >> 11, sv = m0 & (T_SEQ - 1);
                const size_t base = ((((size_t)(bq * NHEAD + hhh) * 64 + (sv >> 5)) * 4 + dmi) * 64
                                    + xt + 16 * ((sv & 15) >> 2)) * 8 + 4 * ((sv >> 4) & 1);
                short4 st;
                st.x = bfs(o[0] + bv); st.y = bfs(o[1] + bv);
                st.z = bfs(o[2] + bv); st.w = bfs(o[3] + bv);
                *(short4*)&Cvf[base] = st;
            }
        }
    }
}

// ---------------------------------------------------------------------------
// Flash attention, fully LDS-free / barrier-free. QBLK=128, 4 waves, each
// owning 2x16 q-rows. QK^T 1-term (K-hi frags from global), PV 2-term
// (V^T-hi frags from global, P hi+lo in-register). XCD-swizzled grid.
// Output: frag-packed u32 y (consumer K2 = CDIM).
// ---------------------------------------------------------------------------
__global__ __launch_bounds__(256) void attn_mfma_kernel(
    const uint* __restrict__ qrow, const short* __restrict__ kf,
    const short* __restrict__ vf, uint* __restrict__ y)
{
    const int tid  = threadIdx.x;
    const int w    = tid >> 6;
    const int lane = tid & 63;
    const int x    = lane & 15;
    const int gl   = lane >> 4;

    const int orig = blockIdx.x;
    const int wgid = (orig & 7) * 64 + (orig >> 3);
    const int bh = wgid >> 4;
    const int b = bh >> 4, hh = bh & 15;
    const int t0 = (wgid & 15) * 128;

    i32x4 qhi[2][2];
#pragma unroll
    for (int qf = 0; qf < 2; ++qf) {
        const uint* qp = qrow + (size_t)(b * T_SEQ + t0 + 64 * qf + 16 * w + x) * 1024 + hh * 64;
#pragma unroll
        for (int ch = 0; ch < 2; ++ch) {
            uint4 a0 = *(const uint4*)(qp + 32 * ch + 4 * gl);
            uint4 a1 = *(const uint4*)(qp + 32 * ch + 16 + 4 * gl);
            qhi[qf][ch][0] = (int)prm(a0.y, a0.x, SELHI); qhi[qf][ch][1] = (int)prm(a0.w, a0.z, SELHI);
            qhi[qf][ch][2] = (int)prm(a1.y, a1.x, SELHI); qhi[qf][ch][3] = (int)prm(a1.w, a1.z, SELHI);
        }
    }

    const short* kb = kf + (size_t)bh * 128 * 2 * 512 + (size_t)lane * 8;
    const short* vb = vf + (size_t)bh * 64 * 4 * 512 + (size_t)lane * 8;

    f32x4 oacc[2][4];
#pragma unroll
    for (int qf = 0; qf < 2; ++qf)
#pragma unroll
        for (int i = 0; i < 4; ++i) oacc[qf][i] = (f32x4){0.f, 0.f, 0.f, 0.f};
    float lsum[2] = {0.f, 0.f};

    for (int s0 = 0; s0 < T_SEQ; s0 += 64) {
        // ---- S^T = K·Q^T (K-hi frags straight from global/L2) ----
        f32x4 s4[2][4];
#pragma unroll
        for (int qf = 0; qf < 2; ++qf)
#pragma unroll
            for (int sc = 0; sc < 4; ++sc) s4[qf][sc] = (f32x4){0.f, 0.f, 0.f, 0.f};
#pragma unroll
        for (int sc = 0; sc < 4; ++sc) {
#pragma unroll
            for (int ch = 0; ch < 2; ++ch) {
                bf16x8 kh = *(const bf16x8*)(kb + ((((size_t)(s0 >> 4) + sc) * 2 + ch) * 512));
                s4[0][sc] = __builtin_amdgcn_mfma_f32_16x16x32_bf16(kh, asb(qhi[0][ch]), s4[0][sc], 0, 0, 0);
                s4[1][sc] = __builtin_amdgcn_mfma_f32_16x16x32_bf16(kh, asb(qhi[1][ch]), s4[1][sc], 0, 0, 0);
            }
        }

        // ---- softmax (no max-sub; |logit| << 1) + P hi/lo pack ----
        i32x4 pfh[2][2], pfl[2][2];
#pragma unroll
        for (int qf = 0; qf < 2; ++qf) {
            f32x4 pc[4];
#pragma unroll
            for (int sc = 0; sc < 4; ++sc) {
                pc[sc][0] = __expf(s4[qf][sc][0] * 0.125f);
                pc[sc][1] = __expf(s4[qf][sc][1] * 0.125f);
                pc[sc][2] = __expf(s4[qf][sc][2] * 0.125f);
                pc[sc][3] = __expf(s4[qf][sc][3] * 0.125f);
                lsum[qf] += pc[sc][0] + pc[sc][1] + pc[sc][2] + pc[sc][3];
            }
#pragma unroll
            for (int c = 0; c < 2; ++c) {
                f32x4 pa = pc[2 * c], pb = pc[2 * c + 1];
                uint a0 = __float_as_uint(pa[0]), a1 = __float_as_uint(pa[1]);
                uint a2 = __float_as_uint(pa[2]), a3 = __float_as_uint(pa[3]);
                uint b0 = __float_as_uint(pb[0]), b1 = __float_as_uint(pb[1]);
                uint b2 = __float_as_uint(pb[2]), b3 = __float_as_uint(pb[3]);
                pfh[qf][c][0] = (int)prm(a1, a0, SELHI); pfh[qf][c][1] = (int)prm(a3, a2, SELHI);
                pfh[qf][c][2] = (int)prm(b1, b0, SELHI); pfh[qf][c][3] = (int)prm(b3, b2, SELHI);
                float d0 = pa[0] - __uint_as_float(a0 & 0xffff0000u);
                float d1 = pa[1] - __uint_as_float(a1 & 0xffff0000u);
                float d2 = pa[2] - __uint_as_float(a2 & 0xffff0000u);
                float d3 = pa[3] - __uint_as_float(a3 & 0xffff0000u);
                float e0 = pb[0] - __uint_as_float(b0 & 0xffff0000u);
                float e1 = pb[1] - __uint_as_float(b1 & 0xffff0000u);
                float e2 = pb[2] - __uint_as_float(b2 & 0xffff0000u);
                float e3 = pb[3] - __uint_as_float(b3 & 0xffff0000u);
                pfl[qf][c][0] = (int)prm(__float_as_uint(d1), __float_as_uint(d0), SELHI);
                pfl[qf][c][1] = (int)prm(__float_as_uint(d3), __float_as_uint(d2), SELHI);
                pfl[qf][c][2] = (int)prm(__float_as_uint(e1), __float_as_uint(e0), SELHI);
                pfl[qf][c][3] = (int)prm(__float_as_uint(e3), __float_as_uint(e2), SELHI);
            }
        }

        // ---- O^T += V^T·P^T (V^T-hi frags straight from global/L2) ----
#pragma unroll
        for (int dm = 0; dm < 4; ++dm) {
#pragma unroll
            for (int ch = 0; ch < 2; ++ch) {
                bf16x8 vh = *(const bf16x8*)(vb + ((((size_t)(s0 >> 5) + ch) * 4 + dm) * 512));
#pragma unroll
                for (int qf = 0; qf < 2; ++qf) {
                    oacc[qf][dm] = __builtin_amdgcn_mfma_f32_16x16x32_bf16(vh, asb(pfh[qf][ch]), oacc[qf][dm], 0, 0, 0);
                    oacc[qf][dm] = __builtin_amdgcn_mfma_f32_16x16x32_bf16(vh, asb(pfl[qf][ch]), oacc[qf][dm], 0, 0, 0);
                }
            }
        }
    }

#pragma unroll
    for (int qf = 0; qf < 2; ++qf) {
        float ls = lsum[qf];
        ls += __shfl_xor(ls, 16);
        ls += __shfl_xor(ls, 32);
        const float invl = 1.f / ls;
        const size_t mt = (size_t)((b * T_SEQ + t0) >> 4) + 4 * qf + w;
#pragma unroll
        for (int dm = 0; dm < 4; ++dm) {
            f32x4 o = oacc[qf][dm];
            const size_t addr = (mt * 32 + hh * 2 + (dm >> 1)) * 512
                              + (size_t)lane * 8 + 4 * (dm & 1);
            uint4 pk;
            pk.x = packsplit(o[0] * invl); pk.y = packsplit(o[1] * invl);
            pk.z = packsplit(o[2] * invl); pk.w = packsplit(o[3] * invl);
            *(uint4*)&y[addr] = pk;
        }
    }
}

// ---------------------------------------------------------------------------
// LayerNorm; input frag-packed u32, output f32 rows.
// ---------------------------------------------------------------------------
__global__ __launch_bounds__(256) void ln_kernel(
    const uint* __restrict__ h, const float* __restrict__ gamma,
    const float* __restrict__ beta, float* __restrict__ out)
{
    const int row = blockIdx.x;
    const int tid = threadIdx.x;

    const size_t addr = ((size_t)(row >> 4) * 32 + (tid >> 3)) * 512
                      + (size_t)((tid & 3) * 16 + (row & 15)) * 8
                      + 4 * ((tid >> 2) & 1);
    uint4 u = *(const uint4*)&h[addr];
    float4 v;
    v.x = unpack2(u.x); v.y = unpack2(u.y); v.z = unpack2(u.z); v.w = unpack2(u.w);

    float s  = v.x + v.y + v.z + v.w;
    float ss = v.x * v.x + v.y * v.y + v.z * v.z + v.w * v.w;
#pragma unroll
    for (int off = 1; off < 64; off <<= 1) {
        s  += __shfl_xor(s, off);
        ss += __shfl_xor(ss, off);
    }
    __shared__ float rs[4], rss[4];
    const int wid = tid >> 6;
    if ((tid & 63) == 0) { rs[wid] = s; rss[wid] = ss; }
    __syncthreads();
    s  = rs[0] + rs[1] + rs[2] + rs[3];
    ss = rss[0] + rss[1] + rss[2] + rss[3];

    const float mu   = s * (1.f / (float)CDIM);
    const float var  = ss * (1.f / (float)CDIM) - mu * mu;
    const float rstd = rsqrtf(var + 1e-5f);

    const float4 g  = *(const float4*)&gamma[tid * 4];
    const float4 be = *(const float4*)&beta[tid * 4];
    float4 o;
    o.x = (v.x - mu) * rstd * g.x + be.x;
    o.y = (v.y - mu) * rstd * g.y + be.y;
    o.z = (v.z - mu) * rstd * g.z + be.z;
    o.w = (v.w - mu) * rstd * g.w + be.w;
    *(float4*)&out[(size_t)row * CDIM + tid * 4] = o;
}

// ---------------------------------------------------------------------------
extern "C" void kernel_launch(void* const* d_in, const int* in_sizes, int n_in,
                              void* d_out, int out_size, void* d_ws, size_t ws_size,
                              hipStream_t stream)
{
    const float* x      = (const float*)d_in[0];
    const float* W_emb  = (const float*)d_in[1];
    const float* b_emb  = (const float*)d_in[2];
    const float* pos    = (const float*)d_in[3];
    const float* Wqkv   = (const float*)d_in[4];
    const float* bqkv   = (const float*)d_in[5];
    const float* Wproj  = (const float*)d_in[6];
    const float* bproj  = (const float*)d_in[7];
    const float* gamma  = (const float*)d_in[8];
    const float* beta   = (const float*)d_in[9];
    const float* W_out  = (const float*)d_in[10];
    const float* b_out  = (const float*)d_in[11];
    float* out = (float*)d_out;

    uint* h    = (uint*)d_ws;                       // [4096][1024] frag-packed
    uint* qrow = h + (size_t)MROWS * CDIM;          // [4096][1024] row-major packed (Q)
    uint* y    = qrow + (size_t)MROWS * CDIM;       // [4096][1024] frag-packed / f32 rows (ln out)
    short* kf  = (short*)(y + (size_t)MROWS * CDIM);            // 32*128*2*512 bf16
    short* vfb = kf + (size_t)32 * 128 * 2 * 512;               // 32*64*4*512 bf16
    short* Bqh = vfb + (size_t)32 * 64 * 4 * 512;
    short* Bql = Bqh + (size_t)3 * CDIM * CDIM;
    short* Bph = Bql + (size_t)3 * CDIM * CDIM;
    short* Bpl = Bph + (size_t)CDIM * CDIM;

    const dim3 blk(256);
    const int nattn = (T_SEQ / 128) * BATCH * NHEAD;  // 512 blocks, 1-D swizzled

    // h(frag) = x @ W_emb + b_emb + pos
    gemm_f32_kernel<<<dim3(CDIM / 64, MROWS / 64), blk, 0, stream>>>(
        x, W_emb, b_emb, pos, (float*)h, MROWS, CDIM, VDIM, T_SEQ, 2);
    for (int l = 0; l < NLAYER; ++l) {
        wsplit_kernel<<<dim3(3 * CDIM / 64, CDIM / 16), blk, 0, stream>>>(
            Wqkv + (size_t)l * CDIM * 3 * CDIM, Bqh, Bql, 3 * CDIM, CDIM);
        gemm_mfma_kernel<<<dim3(3 * CDIM / 128, MROWS / 128), blk, 0, stream>>>(
            h, Bqh, Bql, bqkv + (size_t)l * 3 * CDIM,
            nullptr, qrow, kf, vfb, MROWS, 3 * CDIM, CDIM, 3);
        attn_mfma_kernel<<<dim3(nattn), blk, 0, stream>>>(qrow, kf, vfb, y);
        wsplit_kernel<<<dim3(CDIM / 64, CDIM / 16), blk, 0, stream>>>(
            Wproj + (size_t)l * CDIM * CDIM, Bph, Bpl, CDIM, CDIM);
        gemm_mfma_kernel<<<dim3(CDIM / 128, MROWS / 128), blk, 0, stream>>>(
            y, Bph, Bpl, bproj + (size_t)l * CDIM,
            h, nullptr, nullptr, nullptr, MROWS, CDIM, CDIM, 2);
    }
    ln_kernel<<<dim3(MROWS), blk, 0, stream>>>(h, gamma, beta, (float*)y);
    gemm_f32_kernel<<<dim3(VDIM / 64, MROWS / 64), blk, 0, stream>>>(
        (float*)y, W_out, b_out, nullptr, out, MROWS, VDIM, CDIM, 1, 0);
}